// Round 5
// baseline (376.160 us; speedup 1.0000x reference)
//
#include <hip/hip_runtime.h>
#include <hip/hip_bf16.h>
#include <math.h>

// Shapes
#define B_  4
#define E_  768
#define NH_ 12
#define DH_ 64
#define DFF_ 3072
#define OUT_ 1000
#define S_  197
#define ROWS_ 788          // B_*S_
#define QH_P 12608         // 197*64 per-head q pitch
#define KGP  16384         // 256*64 per-head k / v^T pitch

typedef __bf16 bf16x8_t __attribute__((ext_vector_type(8)));
typedef float f32x4_t __attribute__((ext_vector_type(4)));
typedef _Float16 f16x2_t __attribute__((ext_vector_type(2)));

#define HAS_FDOT2 __has_builtin(__builtin_amdgcn_fdot2)

__device__ __forceinline__ float gelu_f(float x) {
    float x3 = x * x * x;
    return 0.5f * x * (1.0f + tanhf(0.7978845608028654f * (x + 0.044715f * x3)));
}
__device__ __forceinline__ ushort f_to_bf16bits(float f) {
    __hip_bfloat16 b = __float2bfloat16(f);
    return *(ushort*)&b;
}
__device__ __forceinline__ ushort f_to_f16bits(float f) {
    _Float16 h = (_Float16)f;
    return __builtin_bit_cast(ushort, h);
}
__device__ __forceinline__ f16x2_t u2h(uint u) { return __builtin_bit_cast(f16x2_t, u); }
__device__ __forceinline__ f16x2_t min2(f16x2_t a, f16x2_t b) {
    return __builtin_elementwise_min(a, b);
}

// ---------------- merged prologue prep: im2col(x4) + reg-transpose weights + conv cvt(x4) ----------------
#define WT_CONV   0
#define WT_LBASE  589824
#define WT_LSTRIDE 7077888
#define WT_QKV    0
#define WT_PROJ   1769472
#define WT_FC1    2359296
#define WT_FC2    4718592
__global__ __launch_bounds__(256) void prep_all_kernel(const float* __restrict__ x,
                                                       __hip_bfloat16* __restrict__ aim,
                                                       const float* __restrict__ attn_w,
                                                       const float* __restrict__ proj_w,
                                                       const float* __restrict__ fc1_w,
                                                       const float* __restrict__ fc2_w,
                                                       const float* __restrict__ conv_w,
                                                       __hip_bfloat16* __restrict__ wt) {
    int bid = blockIdx.x;
    if (bid < 588) {                        // im2col, 4 elems/thread
        int id = bid * 256 + threadIdx.x;   // 0..150527
        int row = id / 192, k4 = (id - row * 192) * 4;
        int b = row / 196, pr = row - b * 196;
        int hp = pr / 14, wp = pr - hp * 14;
        int c = k4 >> 8, rem = k4 & 255, p = rem >> 4, q = rem & 15;
        float4 v = *(const float4*)&x[(((size_t)(b * 3 + c) * 224) + hp * 16 + p) * 224 + wp * 16 + q];
        ushort4 o = make_ushort4(f_to_bf16bits(v.x), f_to_bf16bits(v.y), f_to_bf16bits(v.z), f_to_bf16bits(v.w));
        *(ushort4*)((ushort*)aim + (size_t)row * 768 + k4) = o;
        return;
    }
    int id = bid - 588;
    if (id < 3456) {                        // 64x64 register transpose tiles
        int l = id / 1728, r = id - l * 1728;
        const float* src;
        __hip_bfloat16* dst;
        int K, N, tile;
        size_t lbase = WT_LBASE + (size_t)l * WT_LSTRIDE;
        if (r < 432)       { src = attn_w + (size_t)l * E_ * 3 * E_; dst = wt + lbase + WT_QKV;  K = E_;   N = 3 * E_; tile = r; }
        else if (r < 576)  { src = proj_w + (size_t)l * E_ * E_;     dst = wt + lbase + WT_PROJ; K = E_;   N = E_;     tile = r - 432; }
        else if (r < 1152) { src = fc1_w + (size_t)l * E_ * DFF_;    dst = wt + lbase + WT_FC1;  K = E_;   N = DFF_;   tile = r - 576; }
        else               { src = fc2_w + (size_t)l * DFF_ * E_;    dst = wt + lbase + WT_FC2;  K = DFF_; N = E_;     tile = r - 1152; }
        int ntn = N >> 6;
        int kb = (tile / ntn) * 64, nb = (tile % ntn) * 64;
        int kq = (threadIdx.x & 15) * 4, nq = (threadIdx.x >> 4) * 4;
        const float* s0 = src + (size_t)(kb + kq) * N + nb + nq;
        float4 v0 = *(const float4*)(s0);
        float4 v1 = *(const float4*)(s0 + N);
        float4 v2 = *(const float4*)(s0 + 2 * N);
        float4 v3 = *(const float4*)(s0 + 3 * N);
        __hip_bfloat16* d0 = dst + (size_t)(nb + nq) * K + kb + kq;
        *(ushort4*)(d0)         = make_ushort4(f_to_bf16bits(v0.x), f_to_bf16bits(v1.x), f_to_bf16bits(v2.x), f_to_bf16bits(v3.x));
        *(ushort4*)(d0 + K)     = make_ushort4(f_to_bf16bits(v0.y), f_to_bf16bits(v1.y), f_to_bf16bits(v2.y), f_to_bf16bits(v3.y));
        *(ushort4*)(d0 + 2 * K) = make_ushort4(f_to_bf16bits(v0.z), f_to_bf16bits(v1.z), f_to_bf16bits(v2.z), f_to_bf16bits(v3.z));
        *(ushort4*)(d0 + 3 * K) = make_ushort4(f_to_bf16bits(v0.w), f_to_bf16bits(v1.w), f_to_bf16bits(v2.w), f_to_bf16bits(v3.w));
        return;
    }
    {                                        // conv cvt (already [N,K]), 4/thread
        int off = ((id - 3456) * 256 + threadIdx.x) * 4;
        float4 v = *(const float4*)&conv_w[off];
        ushort4 o = make_ushort4(f_to_bf16bits(v.x), f_to_bf16bits(v.y), f_to_bf16bits(v.z), f_to_bf16bits(v.w));
        *(ushort4*)((ushort*)wt + WT_CONV + off) = o;
    }
}

// ---------------- MFMA GEMM 64x64: LDS dbuf, prefetch depth 2, split-K, partial n-offset ----------------
#define BK 64
#define AP 72
__global__ __launch_bounds__(256) void gemm_mfma_kernel(const __hip_bfloat16* __restrict__ A,
                                                        const __hip_bfloat16* __restrict__ WT,
                                                        const float* __restrict__ bias,
                                                        const float* __restrict__ res,
                                                        float* __restrict__ Cf,
                                                        __hip_bfloat16* __restrict__ Cb,
                                                        float* __restrict__ partbase,
                                                        int M, int N, int K, int act, int KS,
                                                        int res_pitch, int pn, int nofs) {
    __shared__ __align__(16) ushort Asb[2][64 * AP];
    __shared__ __align__(16) ushort Bsb[2][64 * AP];
    const int tid = threadIdx.x;
    const int wave = tid >> 6, lane = tid & 63;
    const int quad = lane >> 4, l15 = lane & 15;
    const int wm = wave >> 1, wn = wave & 1;
    const int m0 = blockIdx.y * 64, n0 = blockIdx.x * 64;

    const int Kc   = K / KS;
    const int kbeg = blockIdx.z * Kc;
    const int n_it = Kc / BK;

    f32x4_t acc[2][2] = {};

    const int c0r = tid >> 3,         c0o = (tid & 7) * 8;
    const int c1r = (tid + 256) >> 3, c1o = c0o;

    uint4 pa0, pa1, pb0, pb1;
    auto load_tile = [&](int kk) {
        pa0 = make_uint4(0, 0, 0, 0);
        pa1 = pa0;
        int gm = m0 + c0r;
        if (gm < M) pa0 = *(const uint4*)&A[(size_t)gm * K + kk + c0o];
        gm = m0 + c1r;
        if (gm < M) pa1 = *(const uint4*)&A[(size_t)gm * K + kk + c1o];
        pb0 = *(const uint4*)&WT[(size_t)(n0 + c0r) * K + kk + c0o];
        pb1 = *(const uint4*)&WT[(size_t)(n0 + c1r) * K + kk + c1o];
    };
    auto store_tile = [&](int buf) {
        *(uint4*)&Asb[buf][c0r * AP + c0o] = pa0;
        *(uint4*)&Asb[buf][c1r * AP + c1o] = pa1;
        *(uint4*)&Bsb[buf][c0r * AP + c0o] = pb0;
        *(uint4*)&Bsb[buf][c1r * AP + c1o] = pb1;
    };

    load_tile(kbeg);
    store_tile(0);
    if (n_it > 1) load_tile(kbeg + BK);
    __syncthreads();

    for (int it = 0; it < n_it; ++it) {
        const int cur = it & 1, nxt = cur ^ 1;
        if (it + 1 < n_it) {
            store_tile(nxt);
            if (it + 2 < n_it) load_tile(kbeg + (it + 2) * BK);
        }
        const ushort* As = Asb[cur];
        const ushort* Bs = Bsb[cur];
#pragma unroll
        for (int ks = 0; ks < BK; ks += 32) {
            bf16x8_t a0 = *(const bf16x8_t*)&As[(32 * wm + l15) * AP + ks + 8 * quad];
            bf16x8_t a1 = *(const bf16x8_t*)&As[(32 * wm + 16 + l15) * AP + ks + 8 * quad];
            bf16x8_t b0 = *(const bf16x8_t*)&Bs[(32 * wn + l15) * AP + ks + 8 * quad];
            bf16x8_t b1 = *(const bf16x8_t*)&Bs[(32 * wn + 16 + l15) * AP + ks + 8 * quad];
            acc[0][0] = __builtin_amdgcn_mfma_f32_16x16x32_bf16(a0, b0, acc[0][0], 0, 0, 0);
            acc[0][1] = __builtin_amdgcn_mfma_f32_16x16x32_bf16(a0, b1, acc[0][1], 0, 0, 0);
            acc[1][0] = __builtin_amdgcn_mfma_f32_16x16x32_bf16(a1, b0, acc[1][0], 0, 0, 0);
            acc[1][1] = __builtin_amdgcn_mfma_f32_16x16x32_bf16(a1, b1, acc[1][1], 0, 0, 0);
        }
        __syncthreads();
    }

    if (partbase) {
        float* P = partbase + (size_t)blockIdx.z * M * pn;
#pragma unroll
        for (int mi = 0; mi < 2; ++mi)
#pragma unroll
            for (int ni = 0; ni < 2; ++ni) {
                int gn = n0 + 32 * wn + 16 * ni + l15;
#pragma unroll
                for (int r = 0; r < 4; ++r) {
                    int gm = m0 + 32 * wm + 16 * mi + quad * 4 + r;
                    if (gm < M) P[(size_t)gm * pn + nofs + gn] = acc[mi][ni][r];
                }
            }
        return;
    }

#pragma unroll
    for (int mi = 0; mi < 2; ++mi)
#pragma unroll
        for (int ni = 0; ni < 2; ++ni) {
            int gn = n0 + 32 * wn + 16 * ni + l15;
#pragma unroll
            for (int r = 0; r < 4; ++r) {
                int gm = m0 + 32 * wm + 16 * mi + quad * 4 + r;
                if (gm < M) {
                    float v = acc[mi][ni][r] + bias[gn];
                    if (act == 1) v = gelu_f(v);
                    if (res) v += res[(size_t)gm * res_pitch + gn];
                    if (Cf) Cf[(size_t)gm * N + gn] = v;
                    else    Cb[(size_t)gm * N + gn] = __float2bfloat16(v);
                }
            }
        }
}

// ---------------- embed (split-K patch parts + conv_b + pe) + cls + LN1(l=0) fused ----------------
__global__ __launch_bounds__(256) void embed_ln_kernel(const float* __restrict__ p0,
                                                       const float* __restrict__ p1,
                                                       const float* __restrict__ cb,
                                                       const float* __restrict__ pe,
                                                       const float* __restrict__ ct,
                                                       const float* __restrict__ lw,
                                                       const float* __restrict__ lb,
                                                       float* __restrict__ h,
                                                       __hip_bfloat16* __restrict__ y) {
    int row = blockIdx.x, tid = threadIdx.x;
    int b = row / S_, s = row - b * S_;
    float v[3];
#pragma unroll
    for (int c = 0; c < 3; ++c) {
        int e = tid + c * 256;
        float t;
        if (s == 0) t = ct[e];
        else {
            int pr = s - 1;
            size_t gi = (size_t)(b * 196 + pr) * E_ + e;
            t = p0[gi] + p1[gi] + cb[e] + pe[(size_t)pr * E_ + e];
        }
        h[(size_t)row * E_ + e] = t;
        v[c] = t;
    }
    float sm = v[0] + v[1] + v[2];
    float sq = v[0] * v[0] + v[1] * v[1] + v[2] * v[2];
#pragma unroll
    for (int m = 1; m < 64; m <<= 1) {
        sm += __shfl_xor(sm, m, 64);
        sq += __shfl_xor(sq, m, 64);
    }
    __shared__ float ss[4], sqs[4];
    int wave = tid >> 6, lane = tid & 63;
    if (lane == 0) { ss[wave] = sm; sqs[wave] = sq; }
    __syncthreads();
    sm = ss[0] + ss[1] + ss[2] + ss[3];
    sq = sqs[0] + sqs[1] + sqs[2] + sqs[3];
    float mu   = sm * (1.0f / 768.0f);
    float var  = sq * (1.0f / 768.0f) - mu * mu;
    float rstd = rsqrtf(var + 1e-5f);
    __hip_bfloat16* yr = y + (size_t)row * E_;
#pragma unroll
    for (int c = 0; c < 3; ++c) {
        int e = tid + c * 256;
        yr[e] = __float2bfloat16((v[c] - mu) * rstd * lw[e] + lb[e]);
    }
}

// ---------------- LayerNorm (fp32 in, bf16 out) ----------------
__global__ __launch_bounds__(256) void layernorm_kernel(const float* __restrict__ x,
                                                        const float* __restrict__ w,
                                                        const float* __restrict__ b,
                                                        __hip_bfloat16* __restrict__ y) {
    int row = blockIdx.x;
    const float* xr = x + (size_t)row * E_;
    int tid = threadIdx.x;
    float v0 = xr[tid], v1 = xr[tid + 256], v2 = xr[tid + 512];
    float s  = v0 + v1 + v2;
    float sq = v0 * v0 + v1 * v1 + v2 * v2;
#pragma unroll
    for (int m = 1; m < 64; m <<= 1) {
        s  += __shfl_xor(s, m, 64);
        sq += __shfl_xor(sq, m, 64);
    }
    __shared__ float ss[4], sqs[4];
    int wave = tid >> 6, lane = tid & 63;
    if (lane == 0) { ss[wave] = s; sqs[wave] = sq; }
    __syncthreads();
    s  = ss[0] + ss[1] + ss[2] + ss[3];
    sq = sqs[0] + sqs[1] + sqs[2] + sqs[3];
    float mu   = s * (1.0f / 768.0f);
    float var  = sq * (1.0f / 768.0f) - mu * mu;
    float rstd = rsqrtf(var + 1e-5f);
    __hip_bfloat16* yr = y + (size_t)row * E_;
    yr[tid]       = __float2bfloat16((v0 - mu) * rstd * w[tid]       + b[tid]);
    yr[tid + 256] = __float2bfloat16((v1 - mu) * rstd * w[tid + 256] + b[tid + 256]);
    yr[tid + 512] = __float2bfloat16((v2 - mu) * rstd * w[tid + 512] + b[tid + 512]);
}

// ---------------- fused split-K(np) reduce + bias + residual + LayerNorm ----------------
__global__ __launch_bounds__(256) void reduce_ln_kernel(const float* __restrict__ parts,
                                                        int np, size_t pstride,
                                                        const float* __restrict__ bias,
                                                        float* __restrict__ h,
                                                        const float* __restrict__ lw,
                                                        const float* __restrict__ lb,
                                                        __hip_bfloat16* __restrict__ y) {
    int row = blockIdx.x, tid = threadIdx.x;
    float v[3];
#pragma unroll
    for (int c = 0; c < 3; ++c) {
        int e = tid + c * 256;
        size_t gi = (size_t)row * E_ + e;
        float t = bias[e] + h[gi];
        for (int z = 0; z < np; ++z) t += parts[z * pstride + gi];
        h[gi] = t;
        v[c] = t;
    }
    float s  = v[0] + v[1] + v[2];
    float sq = v[0] * v[0] + v[1] * v[1] + v[2] * v[2];
#pragma unroll
    for (int m = 1; m < 64; m <<= 1) {
        s  += __shfl_xor(s, m, 64);
        sq += __shfl_xor(sq, m, 64);
    }
    __shared__ float ss[4], sqs[4];
    int wave = tid >> 6, lane = tid & 63;
    if (lane == 0) { ss[wave] = s; sqs[wave] = sq; }
    __syncthreads();
    s  = ss[0] + ss[1] + ss[2] + ss[3];
    sq = sqs[0] + sqs[1] + sqs[2] + sqs[3];
    float mu   = s * (1.0f / 768.0f);
    float var  = sq * (1.0f / 768.0f) - mu * mu;
    float rstd = rsqrtf(var + 1e-5f);
    __hip_bfloat16* yr = y + (size_t)row * E_;
#pragma unroll
    for (int c = 0; c < 3; ++c) {
        int e = tid + c * 256;
        yr[e] = __float2bfloat16((v[c] - mu) * rstd * lw[e] + lb[e]);
    }
}

// ---------------- attention prep (absorbs QKV split-K reduce + bias), 6 z-slices ----------------
// z=0,1: K rows -> f16 [j][d], pad rows = -64; ks row sums. z=2,3: V^T bf16 [d][j] pitch 256.
// z=4,5: Q. nrows==1 (layer 1): direct matvec from xin @ wraw for the CLS row (z=4 only).
__global__ __launch_bounds__(256) void attn_prep_kernel(const float* __restrict__ p0,
                                                        const float* __restrict__ p1,
                                                        const float* __restrict__ ab,
                                                        ushort* __restrict__ kg,
                                                        float* __restrict__ ksg,
                                                        ushort* __restrict__ qg,
                                                        ushort* __restrict__ vgt,
                                                        float* __restrict__ qsg,
                                                        int nrows,
                                                        const __hip_bfloat16* __restrict__ xin,
                                                        const float* __restrict__ wraw) {
    const int tid = threadIdx.x, lane = tid & 63, wv = tid >> 6;
    const int hh = blockIdx.x, bb = blockIdx.y, z = blockIdx.z;
    const int head = bb * NH_ + hh;
    if (z < 2) {                         // K
        const int jb = z * 128;
        float* ksrow = ksg + (size_t)head * 256;
        for (int c = 0; c < 32; ++c) {
            int j = jb + c * 4 + wv;
            float val;
            if (j < S_) {
                size_t g = ((size_t)(bb * S_ + j)) * (3 * E_) + E_ + hh * DH_ + lane;
                val = fmaxf(p0[g] + p1[g] + ab[E_ + hh * DH_ + lane], 0.f);
            } else val = -64.f;
            kg[(size_t)head * KGP + j * 64 + lane] = f_to_f16bits(val);
            float s = (j < S_) ? val : 0.f;
#pragma unroll
            for (int m = 1; m < 64; m <<= 1) s += __shfl_xor(s, m, 64);
            if (lane == 0) ksrow[j] = s;
        }
    } else if (z < 4) {                  // V transpose
        __shared__ ushort t[64][130];
        const int jb = (z - 2) * 128;
        for (int c = 0; c < 32; ++c) {
            int idx = c * 256 + tid;
            int jl = idx >> 6, d = idx & 63;
            int j = jb + jl;
            float val = 0.f;
            if (j < S_) {
                size_t g = ((size_t)(bb * S_ + j)) * (3 * E_) + 2 * E_ + hh * DH_ + d;
                val = p0[g] + p1[g] + ab[2 * E_ + hh * DH_ + d];
            }
            t[d][jl] = f_to_bf16bits(val);
        }
        __syncthreads();
        for (int c = 0; c < 32; ++c) {
            int idx = c * 256 + tid;
            int d = idx >> 7, jl = idx & 127;
            vgt[(size_t)head * KGP + d * 256 + jb + jl] = t[d][jl];
        }
    } else {                             // Q
        if (nrows == 1) {
            if (z == 5) return;
            __shared__ float sacc[4][64];
            const __hip_bfloat16* xr = xin + (size_t)(bb * S_) * E_;
            const float* wcol = wraw + hh * DH_;
            float acc = 0.f;
            const int k0 = wv * 192;
#pragma unroll 4
            for (int k = k0; k < k0 + 192; ++k)
                acc += __bfloat162float(xr[k]) * wcol[(size_t)k * (3 * E_) + lane];
            sacc[wv][lane] = acc;
            __syncthreads();
            if (tid < 64) {
                float q = sacc[0][tid] + sacc[1][tid] + sacc[2][tid] + sacc[3][tid] + ab[hh * DH_ + tid];
                q = fmaxf(q, 0.f);
                qg[(size_t)head * QH_P + tid] = f_to_f16bits(q);
                float s = q;
#pragma unroll
                for (int m = 1; m < 64; m <<= 1) s += __shfl_xor(s, m, 64);
                if (tid == 0) qsg[(size_t)head * 200] = s;
            }
            return;
        }
        const int ib = (z - 4) * 128;
        float* qsrow = qsg + (size_t)head * 200;
        for (int c = 0; c < 32; ++c) {
            int i = ib + c * 4 + wv;
            if (i >= nrows) continue;    // wave-uniform
            size_t g = ((size_t)(bb * S_ + i)) * (3 * E_) + hh * DH_ + lane;
            float val = fmaxf(p0[g] + p1[g] + ab[hh * DH_ + lane], 0.f);
            qg[(size_t)head * QH_P + i * 64 + lane] = f_to_f16bits(val);
            float s = val;
#pragma unroll
            for (int m = 1; m < 64; m <<= 1) s += __shfl_xor(s, m, 64);
            if (lane == 0) qsrow[i] = s;
        }
    }
}

// ---------------- Tversky attention: score = 2*sum(min(q,k)) / (qs+ks+2eps) ----------------
// launch_bounds(256,3): cap VGPRs <=170 so 3 waves/SIMD fit (was 172 -> 2 waves, latency-exposed).
// K chunks consumed via depth-1 LDS pipeline instead of 16-uint4 preload (frees ~48 VGPRs).
__global__ __launch_bounds__(256, 3) void tversky_attn_kernel(const ushort* __restrict__ qg,
                                                              const ushort* __restrict__ kg,
                                                              const float* __restrict__ ksg,
                                                              const ushort* __restrict__ vgt,
                                                              const float* __restrict__ qsg,
                                                              __hip_bfloat16* __restrict__ ao,
                                                              int nrows) {
    __shared__ __align__(16) ushort kf[16384];   // 256 rows x 64 f16, chunk-swizzled
    __shared__ __align__(16) float ks_l[256];
    __shared__ __align__(16) ushort q_l[1024];   // [wave][4 rows][64] f16
    __shared__ __align__(16) ushort p_l[4096];   // [16 rows][256 j] bf16, swizzled
    __shared__ __align__(16) float den_l[16];

    const int tid = threadIdx.x, wv = tid >> 6, lane = tid & 63;
    const int quad = lane >> 4, l15 = lane & 15;
    const int ch = blockIdx.x, hh = blockIdx.y, bb = blockIdx.z;
    const int head = bb * NH_ + hh;

    {
        const ushort* kgh = kg + (size_t)head * KGP;
#pragma unroll
        for (int g = 0; g < 8; ++g) {
            int idx = g * 256 + tid;
            int row = idx >> 3, c = idx & 7;
            int sw = c ^ ((row >> 1) & 7);
            *(uint4*)&kf[row * 64 + sw * 8] = *(const uint4*)&kgh[idx * 8];
        }
        ks_l[tid] = ksg[(size_t)head * 256 + tid];
    }
    const int i0 = ch * 16 + wv * 4;
    if (lane < 32) {
        int r = lane >> 3, c = lane & 7;
        int i = i0 + r;
        uint4 qv = make_uint4(0, 0, 0, 0);
        if (i < nrows) qv = *(const uint4*)&qg[(size_t)head * QH_P + i * 64 + c * 8];
        *(uint4*)&q_l[wv * 256 + r * 64 + c * 8] = qv;
    }
    float qs_r[4];
#pragma unroll
    for (int r = 0; r < 4; ++r)
        qs_r[r] = (i0 + r < nrows) ? qsg[(size_t)head * 200 + i0 + r] : 0.f;
    __syncthreads();

#if HAS_FDOT2
    const f16x2_t one2 = __builtin_bit_cast(f16x2_t, 0x3C003C00u);
#endif
    float den_r[4] = {0.f, 0.f, 0.f, 0.f};
#pragma unroll
    for (int ph = 0; ph < 2; ++ph) {
        const int jb = ph * 128;
        const int r0 = (jb + 2 * lane) * 64;
        float acc0[4] = {0.f, 0.f, 0.f, 0.f};
        float acc1[4] = {0.f, 0.f, 0.f, 0.f};
        // depth-1 pipelined K-chunk consumption (2 uint4 pairs live, not 16)
        int sw0 = (lane & 7) * 8;                 // c=0 ^ (lane&7)
        uint4 k0n = *(const uint4*)&kf[r0 + sw0];
        uint4 k1n = *(const uint4*)&kf[r0 + 64 + sw0];
#pragma unroll
        for (int c = 0; c < 8; ++c) {
            uint4 k0c = k0n, k1c = k1n;
            if (c < 7) {
                int swn = ((c + 1) ^ (lane & 7)) * 8;
                k0n = *(const uint4*)&kf[r0 + swn];
                k1n = *(const uint4*)&kf[r0 + 64 + swn];
            }
            uint k0p[4] = {k0c.x, k0c.y, k0c.z, k0c.w};
            uint k1p[4] = {k1c.x, k1c.y, k1c.z, k1c.w};
#pragma unroll
            for (int r = 0; r < 4; ++r) {
                uint4 qu = *(const uint4*)&q_l[wv * 256 + r * 64 + c * 8];
                uint qp[4] = {qu.x, qu.y, qu.z, qu.w};
#if HAS_FDOT2
#pragma unroll
                for (int p = 0; p < 4; ++p) {
                    f16x2_t qq = u2h(qp[p]);
                    acc0[r] = __builtin_amdgcn_fdot2(min2(qq, u2h(k0p[p])), one2, acc0[r], false);
                    acc1[r] = __builtin_amdgcn_fdot2(min2(qq, u2h(k1p[p])), one2, acc1[r], false);
                }
#else
                f16x2_t m0 = min2(u2h(qp[0]), u2h(k0p[0]));
                f16x2_t m1 = min2(u2h(qp[0]), u2h(k1p[0]));
#pragma unroll
                for (int p = 1; p < 4; ++p) {
                    m0 = m0 + min2(u2h(qp[p]), u2h(k0p[p]));
                    m1 = m1 + min2(u2h(qp[p]), u2h(k1p[p]));
                }
                acc0[r] += (float)m0[0] + (float)m0[1];
                acc1[r] += (float)m1[0] + (float)m1[1];
#endif
            }
        }
        float2 ks2 = *(const float2*)&ks_l[jb + 2 * lane];
#pragma unroll
        for (int r = 0; r < 4; ++r) {
            float s0 = qs_r[r] + ks2.x, s1 = qs_r[r] + ks2.y;
            float e0 = __expf((2.f * acc0[r]) / (s0 + 2e-8f));
            float e1 = __expf((2.f * acc1[r]) / (s1 + 2e-8f));
            float sum = e0 + e1;
#pragma unroll
            for (int m = 1; m < 64; m <<= 1) sum += __shfl_xor(sum, m, 64);
            den_r[r] += sum;
            uint pw = (uint)f_to_bf16bits(e0) | ((uint)f_to_bf16bits(e1) << 16);
            int i = wv * 4 + r;
            *(uint*)&p_l[(i * 256 + jb + 2 * lane) ^ ((i & 7) * 8)] = pw;
        }
    }
    if (lane == 0) {
#pragma unroll
        for (int r = 0; r < 4; ++r) den_l[wv * 4 + r] = den_r[r];
    }
    __syncthreads();

    const ushort* vb = vgt + (size_t)head * KGP + (size_t)(16 * wv + l15) * 256;
    f32x4_t accv = {0.f, 0.f, 0.f, 0.f};
#pragma unroll
    for (int st = 0; st < 8; ++st) {
        bf16x8_t a = *(const bf16x8_t*)&p_l[(l15 * 256 + st * 32 + quad * 8) ^ ((l15 & 7) * 8)];
        bf16x8_t b = *(const bf16x8_t*)&vb[st * 32 + quad * 8];
        accv = __builtin_amdgcn_mfma_f32_16x16x32_bf16(a, b, accv, 0, 0, 0);
    }
    float4 dv = *(const float4*)&den_l[quad * 4];
    float dar[4] = {dv.x, dv.y, dv.z, dv.w};
#pragma unroll
    for (int t = 0; t < 4; ++t) {
        int ig = ch * 16 + quad * 4 + t;
        if (ig < nrows)
            ao[((size_t)(bb * nrows + ig)) * E_ + hh * DH_ + 16 * wv + l15] =
                __float2bfloat16(accv[t] / dar[t]);
    }
}

// ---------------- head: fused fc2-splitK reduce + final LN + classifier ----------------
__global__ __launch_bounds__(256) void head_ln_kernel(const float* __restrict__ hc,
                                                      const float* __restrict__ pc0,
                                                      const float* __restrict__ pc1,
                                                      const float* __restrict__ fb,
                                                      const float* __restrict__ lw,
                                                      const float* __restrict__ lb,
                                                      const float* __restrict__ hw,
                                                      const float* __restrict__ hb,
                                                      float* __restrict__ out) {
    int b = blockIdx.y;
    int tid = threadIdx.x;
    const float* xr0 = hc  + (size_t)b * E_;
    const float* pr0 = pc0 + (size_t)b * E_;
    const float* pr1 = pc1 + (size_t)b * E_;
    float v0 = xr0[tid]       + pr0[tid]       + pr1[tid]       + fb[tid];
    float v1 = xr0[tid + 256] + pr0[tid + 256] + pr1[tid + 256] + fb[tid + 256];
    float v2 = xr0[tid + 512] + pr0[tid + 512] + pr1[tid + 512] + fb[tid + 512];
    float s  = v0 + v1 + v2;
    float sq = v0 * v0 + v1 * v1 + v2 * v2;
#pragma unroll
    for (int m = 1; m < 64; m <<= 1) {
        s  += __shfl_xor(s, m, 64);
        sq += __shfl_xor(sq, m, 64);
    }
    __shared__ float ss[4], sqs[4];
    __shared__ float xr[E_];
    __shared__ float partial[4][64];
    int wave = tid >> 6, lane = tid & 63;
    if (lane == 0) { ss[wave] = s; sqs[wave] = sq; }
    __syncthreads();
    s  = ss[0] + ss[1] + ss[2] + ss[3];
    sq = sqs[0] + sqs[1] + sqs[2] + sqs[3];
    float mu   = s * (1.0f / 768.0f);
    float var  = sq * (1.0f / 768.0f) - mu * mu;
    float rstd = rsqrtf(var + 1e-5f);
    xr[tid]       = (v0 - mu) * rstd * lw[tid]       + lb[tid];
    xr[tid + 256] = (v1 - mu) * rstd * lw[tid + 256] + lb[tid + 256];
    xr[tid + 512] = (v2 - mu) * rstd * lw[tid + 512] + lb[tid + 512];
    __syncthreads();
    int nl = tid & 63, eq = tid >> 6;
    int n = blockIdx.x * 64 + nl;
    float acc = 0.f;
    if (n < OUT_) {
        int e0 = eq * 192;
        for (int e = e0; e < e0 + 192; ++e) acc += xr[e] * hw[(size_t)e * OUT_ + n];
    }
    partial[eq][nl] = acc;
    __syncthreads();
    if (eq == 0 && n < OUT_)
        out[(size_t)b * OUT_ + n] = partial[0][nl] + partial[1][nl] + partial[2][nl] + partial[3][nl] + hb[n];
}

extern "C" void kernel_launch(void* const* d_in, const int* in_sizes, int n_in,
                              void* d_out, int out_size, void* d_ws, size_t ws_size,
                              hipStream_t stream) {
    const float* x        = (const float*)d_in[0];
    const float* conv_w   = (const float*)d_in[1];
    const float* conv_b   = (const float*)d_in[2];
    const float* pos_e    = (const float*)d_in[3];
    const float* cls_t    = (const float*)d_in[4];
    const float* ln1_w    = (const float*)d_in[5];
    const float* ln1_b    = (const float*)d_in[6];
    const float* attn_w   = (const float*)d_in[7];
    const float* attn_b   = (const float*)d_in[8];
    const float* proj_w   = (const float*)d_in[9];
    const float* proj_b   = (const float*)d_in[10];
    const float* ln2_w    = (const float*)d_in[11];
    const float* ln2_b    = (const float*)d_in[12];
    const float* fc1_w    = (const float*)d_in[13];
    const float* fc1_b    = (const float*)d_in[14];
    const float* fc2_w    = (const float*)d_in[15];
    const float* fc2_b    = (const float*)d_in[16];
    const float* lnf_w    = (const float*)d_in[17];
    const float* lnf_b    = (const float*)d_in[18];
    const float* head_w   = (const float*)d_in[19];
    const float* head_b   = (const float*)d_in[20];
    float* out = (float*)d_out;

    // workspace layout
    float* h       = (float*)d_ws;                 // 605184
    float* part0q  = h + 605184;                   // 2x1815552 (QKV parts, contiguous)
    float* part1q  = part0q + 1815552;
    float* part    = part1q + 1815552;             // 2x605184 (patch/proj/fc2 parts)
    float* hc      = part + 3631104;               // 3072
    float* partc   = hc + 3072;                    // 6144
    float* ksg     = partc + 6144;                 // 12288
    float* qsg     = ksg + 12288;                  // 9600
    __hip_bfloat16* lnb  = (__hip_bfloat16*)(qsg + 9600);   // 605184
    __hip_bfloat16* ao   = lnb + 605184;                    // 605184
    __hip_bfloat16* hid  = ao + 605184;                     // 2420736
    __hip_bfloat16* aim  = hid + 2420736;                   // 602112
    __hip_bfloat16* wt   = aim + 602112;                    // 14745600
    ushort* kg  = (ushort*)(wt + 14745600);                 // 786432
    ushort* vgt = kg + 786432;                              // 786432
    ushort* qg  = vgt + 786432;                             // 605184
    __hip_bfloat16* lnb4 = (__hip_bfloat16*)(qg + 605184);  // 3072
    __hip_bfloat16* hid4 = lnb4 + 3072;                     // 12288

    // ---- prologue ----
    prep_all_kernel<<<4620, 256, 0, stream>>>(x, aim, attn_w, proj_w, fc1_w, fc2_w, conv_w, wt);
    {
        dim3 grid(E_ / 64, 13, 2);
        gemm_mfma_kernel<<<grid, 256, 0, stream>>>(aim, wt + WT_CONV, nullptr, nullptr, nullptr,
                                                   nullptr, part, 784, E_, E_, 0, 2, 0, E_, 0);
    }
    embed_ln_kernel<<<ROWS_, 256, 0, stream>>>(part, part + 602112, conv_b,
                                               pos_e, cls_t, ln1_w, ln1_b, h, lnb);

    // ---- layer 0 (full 788 rows) ----
    {
        const __hip_bfloat16* wl = wt + WT_LBASE;
        {
            dim3 grid((3 * E_) / 64, 13, 2);
            gemm_mfma_kernel<<<grid, 256, 0, stream>>>(lnb, wl + WT_QKV, nullptr, nullptr,
                                                       nullptr, nullptr, part0q,
                                                       ROWS_, 3 * E_, E_, 0, 2, 0, 3 * E_, 0);
        }
        attn_prep_kernel<<<dim3(NH_, B_, 6), 256, 0, stream>>>(
            part0q, part1q, attn_b, kg, ksg, qg, vgt, qsg, S_, lnb, attn_w);
        tversky_attn_kernel<<<dim3(13, NH_, B_), 256, 0, stream>>>(
            qg, kg, ksg, vgt, qsg, ao, S_);
        {
            dim3 grid(E_ / 64, 13, 2);
            gemm_mfma_kernel<<<grid, 256, 0, stream>>>(ao, wl + WT_PROJ, nullptr, nullptr, nullptr,
                                                       nullptr, part, ROWS_, E_, E_, 0, 2, 0, E_, 0);
        }
        reduce_ln_kernel<<<ROWS_, 256, 0, stream>>>(part, 2, 605184, proj_b,
                                                    h, ln2_w, ln2_b, lnb);
        {
            dim3 grid(DFF_ / 64, 13);
            gemm_mfma_kernel<<<grid, 256, 0, stream>>>(lnb, wl + WT_FC1, fc1_b,
                                                       nullptr, nullptr, hid, nullptr,
                                                       ROWS_, DFF_, E_, 1, 1, 0, DFF_, 0);
        }
        {
            dim3 grid(E_ / 64, 13, 2);
            gemm_mfma_kernel<<<grid, 256, 0, stream>>>(hid, wl + WT_FC2, nullptr, nullptr, nullptr,
                                                       nullptr, part, ROWS_, E_, DFF_, 0, 2, 0, E_, 0);
        }
        reduce_ln_kernel<<<ROWS_, 256, 0, stream>>>(part, 2, 605184, fc2_b,
                                                    h, ln1_w + E_, ln1_b + E_, lnb);
    }

    // ---- layer 1: only CLS rows (4) needed downstream; QKV computes K,V only ----
    {
        const __hip_bfloat16* wl = wt + WT_LBASE + WT_LSTRIDE;
        {
            // N=1536 (K,V cols 768..2304); WT offset skips Q rows; partials at n-offset 768
            dim3 grid(1536 / 64, 13, 2);
            gemm_mfma_kernel<<<grid, 256, 0, stream>>>(lnb, wl + WT_QKV + 768 * E_, nullptr, nullptr,
                                                       nullptr, nullptr, part0q,
                                                       ROWS_, 1536, E_, 0, 2, 0, 3 * E_, 768);
        }
        attn_prep_kernel<<<dim3(NH_, B_, 6), 256, 0, stream>>>(
            part0q, part1q, attn_b + 3 * E_, kg, ksg, qg, vgt, qsg, 1,
            lnb, attn_w + (size_t)E_ * 3 * E_);
        tversky_attn_kernel<<<dim3(1, NH_, B_), 256, 0, stream>>>(
            qg, kg, ksg, vgt, qsg, ao, 1);
        {
            dim3 grid(E_ / 64, 1, 1);
            gemm_mfma_kernel<<<grid, 256, 0, stream>>>(ao, wl + WT_PROJ, proj_b + E_, h,
                                                       hc, nullptr, nullptr,
                                                       4, E_, E_, 0, 1, S_ * E_, E_, 0);
        }
        layernorm_kernel<<<4, 256, 0, stream>>>(hc, ln2_w + E_, ln2_b + E_, lnb4);
        {
            dim3 grid(DFF_ / 64, 1, 1);
            gemm_mfma_kernel<<<grid, 256, 0, stream>>>(lnb4, wl + WT_FC1, fc1_b + DFF_,
                                                       nullptr, nullptr, hid4, nullptr,
                                                       4, DFF_, E_, 1, 1, 0, DFF_, 0);
        }
        {
            dim3 grid(E_ / 64, 1, 2);
            gemm_mfma_kernel<<<grid, 256, 0, stream>>>(hid4, wl + WT_FC2, nullptr, nullptr, nullptr,
                                                       nullptr, partc, 4, E_, DFF_, 0, 2, 0, E_, 0);
        }
    }

    {
        dim3 grid((OUT_ + 63) / 64, B_);
        head_ln_kernel<<<grid, 256, 0, stream>>>(hc, partc, partc + 3072, fc2_b + E_,
                                                 lnf_w, lnf_b, head_w, head_b, out);
    }
}

// Round 6
// 332.064 us; speedup vs baseline: 1.1328x; 1.1328x over previous
//
#include <hip/hip_runtime.h>
#include <hip/hip_bf16.h>
#include <math.h>

// Shapes
#define B_  4
#define E_  768
#define NH_ 12
#define DH_ 64
#define DFF_ 3072
#define OUT_ 1000
#define S_  197
#define ROWS_ 788          // B_*S_
#define QH_P 12608         // 197*64 per-head q pitch
#define KGP  16384         // 256*64 per-head k / v^T pitch

typedef __bf16 bf16x8_t __attribute__((ext_vector_type(8)));
typedef float f32x4_t __attribute__((ext_vector_type(4)));
typedef _Float16 f16x2_t __attribute__((ext_vector_type(2)));

#define HAS_FDOT2 __has_builtin(__builtin_amdgcn_fdot2)

__device__ __forceinline__ float gelu_f(float x) {
    float x3 = x * x * x;
    return 0.5f * x * (1.0f + tanhf(0.7978845608028654f * (x + 0.044715f * x3)));
}
__device__ __forceinline__ ushort f_to_bf16bits(float f) {
    __hip_bfloat16 b = __float2bfloat16(f);
    return *(ushort*)&b;
}
__device__ __forceinline__ ushort f_to_f16bits(float f) {
    _Float16 h = (_Float16)f;
    return __builtin_bit_cast(ushort, h);
}
__device__ __forceinline__ f16x2_t u2h(uint u) { return __builtin_bit_cast(f16x2_t, u); }
__device__ __forceinline__ f16x2_t min2(f16x2_t a, f16x2_t b) {
    return __builtin_elementwise_min(a, b);
}

// ---------------- merged prologue prep: im2col(x4) + reg-transpose weights + conv cvt(x4) ----------------
#define WT_CONV   0
#define WT_LBASE  589824
#define WT_LSTRIDE 7077888
#define WT_QKV    0
#define WT_PROJ   1769472
#define WT_FC1    2359296
#define WT_FC2    4718592
__global__ __launch_bounds__(256) void prep_all_kernel(const float* __restrict__ x,
                                                       __hip_bfloat16* __restrict__ aim,
                                                       const float* __restrict__ attn_w,
                                                       const float* __restrict__ proj_w,
                                                       const float* __restrict__ fc1_w,
                                                       const float* __restrict__ fc2_w,
                                                       const float* __restrict__ conv_w,
                                                       __hip_bfloat16* __restrict__ wt) {
    int bid = blockIdx.x;
    if (bid < 588) {                        // im2col, 4 elems/thread
        int id = bid * 256 + threadIdx.x;   // 0..150527
        int row = id / 192, k4 = (id - row * 192) * 4;
        int b = row / 196, pr = row - b * 196;
        int hp = pr / 14, wp = pr - hp * 14;
        int c = k4 >> 8, rem = k4 & 255, p = rem >> 4, q = rem & 15;
        float4 v = *(const float4*)&x[(((size_t)(b * 3 + c) * 224) + hp * 16 + p) * 224 + wp * 16 + q];
        ushort4 o = make_ushort4(f_to_bf16bits(v.x), f_to_bf16bits(v.y), f_to_bf16bits(v.z), f_to_bf16bits(v.w));
        *(ushort4*)((ushort*)aim + (size_t)row * 768 + k4) = o;
        return;
    }
    int id = bid - 588;
    if (id < 3456) {                        // 64x64 register transpose tiles
        int l = id / 1728, r = id - l * 1728;
        const float* src;
        __hip_bfloat16* dst;
        int K, N, tile;
        size_t lbase = WT_LBASE + (size_t)l * WT_LSTRIDE;
        if (r < 432)       { src = attn_w + (size_t)l * E_ * 3 * E_; dst = wt + lbase + WT_QKV;  K = E_;   N = 3 * E_; tile = r; }
        else if (r < 576)  { src = proj_w + (size_t)l * E_ * E_;     dst = wt + lbase + WT_PROJ; K = E_;   N = E_;     tile = r - 432; }
        else if (r < 1152) { src = fc1_w + (size_t)l * E_ * DFF_;    dst = wt + lbase + WT_FC1;  K = E_;   N = DFF_;   tile = r - 576; }
        else               { src = fc2_w + (size_t)l * DFF_ * E_;    dst = wt + lbase + WT_FC2;  K = DFF_; N = E_;     tile = r - 1152; }
        int ntn = N >> 6;
        int kb = (tile / ntn) * 64, nb = (tile % ntn) * 64;
        int kq = (threadIdx.x & 15) * 4, nq = (threadIdx.x >> 4) * 4;
        const float* s0 = src + (size_t)(kb + kq) * N + nb + nq;
        float4 v0 = *(const float4*)(s0);
        float4 v1 = *(const float4*)(s0 + N);
        float4 v2 = *(const float4*)(s0 + 2 * N);
        float4 v3 = *(const float4*)(s0 + 3 * N);
        __hip_bfloat16* d0 = dst + (size_t)(nb + nq) * K + kb + kq;
        *(ushort4*)(d0)         = make_ushort4(f_to_bf16bits(v0.x), f_to_bf16bits(v1.x), f_to_bf16bits(v2.x), f_to_bf16bits(v3.x));
        *(ushort4*)(d0 + K)     = make_ushort4(f_to_bf16bits(v0.y), f_to_bf16bits(v1.y), f_to_bf16bits(v2.y), f_to_bf16bits(v3.y));
        *(ushort4*)(d0 + 2 * K) = make_ushort4(f_to_bf16bits(v0.z), f_to_bf16bits(v1.z), f_to_bf16bits(v2.z), f_to_bf16bits(v3.z));
        *(ushort4*)(d0 + 3 * K) = make_ushort4(f_to_bf16bits(v0.w), f_to_bf16bits(v1.w), f_to_bf16bits(v2.w), f_to_bf16bits(v3.w));
        return;
    }
    {                                        // conv cvt (already [N,K]), 4/thread
        int off = ((id - 3456) * 256 + threadIdx.x) * 4;
        float4 v = *(const float4*)&conv_w[off];
        ushort4 o = make_ushort4(f_to_bf16bits(v.x), f_to_bf16bits(v.y), f_to_bf16bits(v.z), f_to_bf16bits(v.w));
        *(ushort4*)((ushort*)wt + WT_CONV + off) = o;
    }
}

// ---------------- MFMA GEMM 64x64: LDS dbuf, prefetch depth 2, split-K, partial n-offset ----------------
#define BK 64
#define AP 72
__global__ __launch_bounds__(256) void gemm_mfma_kernel(const __hip_bfloat16* __restrict__ A,
                                                        const __hip_bfloat16* __restrict__ WT,
                                                        const float* __restrict__ bias,
                                                        const float* __restrict__ res,
                                                        float* __restrict__ Cf,
                                                        __hip_bfloat16* __restrict__ Cb,
                                                        float* __restrict__ partbase,
                                                        int M, int N, int K, int act, int KS,
                                                        int res_pitch, int pn, int nofs) {
    __shared__ __align__(16) ushort Asb[2][64 * AP];
    __shared__ __align__(16) ushort Bsb[2][64 * AP];
    const int tid = threadIdx.x;
    const int wave = tid >> 6, lane = tid & 63;
    const int quad = lane >> 4, l15 = lane & 15;
    const int wm = wave >> 1, wn = wave & 1;
    const int m0 = blockIdx.y * 64, n0 = blockIdx.x * 64;

    const int Kc   = K / KS;
    const int kbeg = blockIdx.z * Kc;
    const int n_it = Kc / BK;

    f32x4_t acc[2][2] = {};

    const int c0r = tid >> 3,         c0o = (tid & 7) * 8;
    const int c1r = (tid + 256) >> 3, c1o = c0o;

    uint4 pa0, pa1, pb0, pb1;
    auto load_tile = [&](int kk) {
        pa0 = make_uint4(0, 0, 0, 0);
        pa1 = pa0;
        int gm = m0 + c0r;
        if (gm < M) pa0 = *(const uint4*)&A[(size_t)gm * K + kk + c0o];
        gm = m0 + c1r;
        if (gm < M) pa1 = *(const uint4*)&A[(size_t)gm * K + kk + c1o];
        pb0 = *(const uint4*)&WT[(size_t)(n0 + c0r) * K + kk + c0o];
        pb1 = *(const uint4*)&WT[(size_t)(n0 + c1r) * K + kk + c1o];
    };
    auto store_tile = [&](int buf) {
        *(uint4*)&Asb[buf][c0r * AP + c0o] = pa0;
        *(uint4*)&Asb[buf][c1r * AP + c1o] = pa1;
        *(uint4*)&Bsb[buf][c0r * AP + c0o] = pb0;
        *(uint4*)&Bsb[buf][c1r * AP + c1o] = pb1;
    };

    load_tile(kbeg);
    store_tile(0);
    if (n_it > 1) load_tile(kbeg + BK);
    __syncthreads();

    for (int it = 0; it < n_it; ++it) {
        const int cur = it & 1, nxt = cur ^ 1;
        if (it + 1 < n_it) {
            store_tile(nxt);
            if (it + 2 < n_it) load_tile(kbeg + (it + 2) * BK);
        }
        const ushort* As = Asb[cur];
        const ushort* Bs = Bsb[cur];
#pragma unroll
        for (int ks = 0; ks < BK; ks += 32) {
            bf16x8_t a0 = *(const bf16x8_t*)&As[(32 * wm + l15) * AP + ks + 8 * quad];
            bf16x8_t a1 = *(const bf16x8_t*)&As[(32 * wm + 16 + l15) * AP + ks + 8 * quad];
            bf16x8_t b0 = *(const bf16x8_t*)&Bs[(32 * wn + l15) * AP + ks + 8 * quad];
            bf16x8_t b1 = *(const bf16x8_t*)&Bs[(32 * wn + 16 + l15) * AP + ks + 8 * quad];
            acc[0][0] = __builtin_amdgcn_mfma_f32_16x16x32_bf16(a0, b0, acc[0][0], 0, 0, 0);
            acc[0][1] = __builtin_amdgcn_mfma_f32_16x16x32_bf16(a0, b1, acc[0][1], 0, 0, 0);
            acc[1][0] = __builtin_amdgcn_mfma_f32_16x16x32_bf16(a1, b0, acc[1][0], 0, 0, 0);
            acc[1][1] = __builtin_amdgcn_mfma_f32_16x16x32_bf16(a1, b1, acc[1][1], 0, 0, 0);
        }
        __syncthreads();
    }

    if (partbase) {
        float* P = partbase + (size_t)blockIdx.z * M * pn;
#pragma unroll
        for (int mi = 0; mi < 2; ++mi)
#pragma unroll
            for (int ni = 0; ni < 2; ++ni) {
                int gn = n0 + 32 * wn + 16 * ni + l15;
#pragma unroll
                for (int r = 0; r < 4; ++r) {
                    int gm = m0 + 32 * wm + 16 * mi + quad * 4 + r;
                    if (gm < M) P[(size_t)gm * pn + nofs + gn] = acc[mi][ni][r];
                }
            }
        return;
    }

#pragma unroll
    for (int mi = 0; mi < 2; ++mi)
#pragma unroll
        for (int ni = 0; ni < 2; ++ni) {
            int gn = n0 + 32 * wn + 16 * ni + l15;
#pragma unroll
            for (int r = 0; r < 4; ++r) {
                int gm = m0 + 32 * wm + 16 * mi + quad * 4 + r;
                if (gm < M) {
                    float v = acc[mi][ni][r] + bias[gn];
                    if (act == 1) v = gelu_f(v);
                    if (res) v += res[(size_t)gm * res_pitch + gn];
                    if (Cf) Cf[(size_t)gm * N + gn] = v;
                    else    Cb[(size_t)gm * N + gn] = __float2bfloat16(v);
                }
            }
        }
}

// ---------------- embed (split-K patch parts + conv_b + pe) + cls + LN1(l=0) fused ----------------
__global__ __launch_bounds__(256) void embed_ln_kernel(const float* __restrict__ p0,
                                                       const float* __restrict__ p1,
                                                       const float* __restrict__ cb,
                                                       const float* __restrict__ pe,
                                                       const float* __restrict__ ct,
                                                       const float* __restrict__ lw,
                                                       const float* __restrict__ lb,
                                                       float* __restrict__ h,
                                                       __hip_bfloat16* __restrict__ y) {
    int row = blockIdx.x, tid = threadIdx.x;
    int b = row / S_, s = row - b * S_;
    float v[3];
#pragma unroll
    for (int c = 0; c < 3; ++c) {
        int e = tid + c * 256;
        float t;
        if (s == 0) t = ct[e];
        else {
            int pr = s - 1;
            size_t gi = (size_t)(b * 196 + pr) * E_ + e;
            t = p0[gi] + p1[gi] + cb[e] + pe[(size_t)pr * E_ + e];
        }
        h[(size_t)row * E_ + e] = t;
        v[c] = t;
    }
    float sm = v[0] + v[1] + v[2];
    float sq = v[0] * v[0] + v[1] * v[1] + v[2] * v[2];
#pragma unroll
    for (int m = 1; m < 64; m <<= 1) {
        sm += __shfl_xor(sm, m, 64);
        sq += __shfl_xor(sq, m, 64);
    }
    __shared__ float ss[4], sqs[4];
    int wave = tid >> 6, lane = tid & 63;
    if (lane == 0) { ss[wave] = sm; sqs[wave] = sq; }
    __syncthreads();
    sm = ss[0] + ss[1] + ss[2] + ss[3];
    sq = sqs[0] + sqs[1] + sqs[2] + sqs[3];
    float mu   = sm * (1.0f / 768.0f);
    float var  = sq * (1.0f / 768.0f) - mu * mu;
    float rstd = rsqrtf(var + 1e-5f);
    __hip_bfloat16* yr = y + (size_t)row * E_;
#pragma unroll
    for (int c = 0; c < 3; ++c) {
        int e = tid + c * 256;
        yr[e] = __float2bfloat16((v[c] - mu) * rstd * lw[e] + lb[e]);
    }
}

// ---------------- LayerNorm (fp32 in, bf16 out) ----------------
__global__ __launch_bounds__(256) void layernorm_kernel(const float* __restrict__ x,
                                                        const float* __restrict__ w,
                                                        const float* __restrict__ b,
                                                        __hip_bfloat16* __restrict__ y) {
    int row = blockIdx.x;
    const float* xr = x + (size_t)row * E_;
    int tid = threadIdx.x;
    float v0 = xr[tid], v1 = xr[tid + 256], v2 = xr[tid + 512];
    float s  = v0 + v1 + v2;
    float sq = v0 * v0 + v1 * v1 + v2 * v2;
#pragma unroll
    for (int m = 1; m < 64; m <<= 1) {
        s  += __shfl_xor(s, m, 64);
        sq += __shfl_xor(sq, m, 64);
    }
    __shared__ float ss[4], sqs[4];
    int wave = tid >> 6, lane = tid & 63;
    if (lane == 0) { ss[wave] = s; sqs[wave] = sq; }
    __syncthreads();
    s  = ss[0] + ss[1] + ss[2] + ss[3];
    sq = sqs[0] + sqs[1] + sqs[2] + sqs[3];
    float mu   = s * (1.0f / 768.0f);
    float var  = sq * (1.0f / 768.0f) - mu * mu;
    float rstd = rsqrtf(var + 1e-5f);
    __hip_bfloat16* yr = y + (size_t)row * E_;
    yr[tid]       = __float2bfloat16((v0 - mu) * rstd * w[tid]       + b[tid]);
    yr[tid + 256] = __float2bfloat16((v1 - mu) * rstd * w[tid + 256] + b[tid + 256]);
    yr[tid + 512] = __float2bfloat16((v2 - mu) * rstd * w[tid + 512] + b[tid + 512]);
}

// ---------------- fused split-K(np) reduce + bias + residual + LayerNorm ----------------
__global__ __launch_bounds__(256) void reduce_ln_kernel(const float* __restrict__ parts,
                                                        int np, size_t pstride,
                                                        const float* __restrict__ bias,
                                                        float* __restrict__ h,
                                                        const float* __restrict__ lw,
                                                        const float* __restrict__ lb,
                                                        __hip_bfloat16* __restrict__ y) {
    int row = blockIdx.x, tid = threadIdx.x;
    float v[3];
#pragma unroll
    for (int c = 0; c < 3; ++c) {
        int e = tid + c * 256;
        size_t gi = (size_t)row * E_ + e;
        float t = bias[e] + h[gi];
        for (int z = 0; z < np; ++z) t += parts[z * pstride + gi];
        h[gi] = t;
        v[c] = t;
    }
    float s  = v[0] + v[1] + v[2];
    float sq = v[0] * v[0] + v[1] * v[1] + v[2] * v[2];
#pragma unroll
    for (int m = 1; m < 64; m <<= 1) {
        s  += __shfl_xor(s, m, 64);
        sq += __shfl_xor(sq, m, 64);
    }
    __shared__ float ss[4], sqs[4];
    int wave = tid >> 6, lane = tid & 63;
    if (lane == 0) { ss[wave] = s; sqs[wave] = sq; }
    __syncthreads();
    s  = ss[0] + ss[1] + ss[2] + ss[3];
    sq = sqs[0] + sqs[1] + sqs[2] + sqs[3];
    float mu   = s * (1.0f / 768.0f);
    float var  = sq * (1.0f / 768.0f) - mu * mu;
    float rstd = rsqrtf(var + 1e-5f);
    __hip_bfloat16* yr = y + (size_t)row * E_;
#pragma unroll
    for (int c = 0; c < 3; ++c) {
        int e = tid + c * 256;
        yr[e] = __float2bfloat16((v[c] - mu) * rstd * lw[e] + lb[e]);
    }
}

// ---------------- attention prep (absorbs QKV split-K reduce + bias), 6 z-slices ----------------
// z=0,1: K rows -> f16 [j][d], pad rows = -64; ks row sums. z=2,3: V^T bf16 [d][j] pitch 256.
// z=4,5: Q. nrows==1 (layer 1): direct matvec from xin @ wraw for the CLS row (z=4 only).
__global__ __launch_bounds__(256) void attn_prep_kernel(const float* __restrict__ p0,
                                                        const float* __restrict__ p1,
                                                        const float* __restrict__ ab,
                                                        ushort* __restrict__ kg,
                                                        float* __restrict__ ksg,
                                                        ushort* __restrict__ qg,
                                                        ushort* __restrict__ vgt,
                                                        float* __restrict__ qsg,
                                                        int nrows,
                                                        const __hip_bfloat16* __restrict__ xin,
                                                        const float* __restrict__ wraw) {
    const int tid = threadIdx.x, lane = tid & 63, wv = tid >> 6;
    const int hh = blockIdx.x, bb = blockIdx.y, z = blockIdx.z;
    const int head = bb * NH_ + hh;
    if (z < 2) {                         // K
        const int jb = z * 128;
        float* ksrow = ksg + (size_t)head * 256;
        for (int c = 0; c < 32; ++c) {
            int j = jb + c * 4 + wv;
            float val;
            if (j < S_) {
                size_t g = ((size_t)(bb * S_ + j)) * (3 * E_) + E_ + hh * DH_ + lane;
                val = fmaxf(p0[g] + p1[g] + ab[E_ + hh * DH_ + lane], 0.f);
            } else val = -64.f;
            kg[(size_t)head * KGP + j * 64 + lane] = f_to_f16bits(val);
            float s = (j < S_) ? val : 0.f;
#pragma unroll
            for (int m = 1; m < 64; m <<= 1) s += __shfl_xor(s, m, 64);
            if (lane == 0) ksrow[j] = s;
        }
    } else if (z < 4) {                  // V transpose
        __shared__ ushort t[64][130];
        const int jb = (z - 2) * 128;
        for (int c = 0; c < 32; ++c) {
            int idx = c * 256 + tid;
            int jl = idx >> 6, d = idx & 63;
            int j = jb + jl;
            float val = 0.f;
            if (j < S_) {
                size_t g = ((size_t)(bb * S_ + j)) * (3 * E_) + 2 * E_ + hh * DH_ + d;
                val = p0[g] + p1[g] + ab[2 * E_ + hh * DH_ + d];
            }
            t[d][jl] = f_to_bf16bits(val);
        }
        __syncthreads();
        for (int c = 0; c < 32; ++c) {
            int idx = c * 256 + tid;
            int d = idx >> 7, jl = idx & 127;
            vgt[(size_t)head * KGP + d * 256 + jb + jl] = t[d][jl];
        }
    } else {                             // Q
        if (nrows == 1) {
            if (z == 5) return;
            __shared__ float sacc[4][64];
            const __hip_bfloat16* xr = xin + (size_t)(bb * S_) * E_;
            const float* wcol = wraw + hh * DH_;
            float acc = 0.f;
            const int k0 = wv * 192;
#pragma unroll 4
            for (int k = k0; k < k0 + 192; ++k)
                acc += __bfloat162float(xr[k]) * wcol[(size_t)k * (3 * E_) + lane];
            sacc[wv][lane] = acc;
            __syncthreads();
            if (tid < 64) {
                float q = sacc[0][tid] + sacc[1][tid] + sacc[2][tid] + sacc[3][tid] + ab[hh * DH_ + tid];
                q = fmaxf(q, 0.f);
                qg[(size_t)head * QH_P + tid] = f_to_f16bits(q);
                float s = q;
#pragma unroll
                for (int m = 1; m < 64; m <<= 1) s += __shfl_xor(s, m, 64);
                if (tid == 0) qsg[(size_t)head * 200] = s;
            }
            return;
        }
        const int ib = (z - 4) * 128;
        float* qsrow = qsg + (size_t)head * 200;
        for (int c = 0; c < 32; ++c) {
            int i = ib + c * 4 + wv;
            if (i >= nrows) continue;    // wave-uniform
            size_t g = ((size_t)(bb * S_ + i)) * (3 * E_) + hh * DH_ + lane;
            float val = fmaxf(p0[g] + p1[g] + ab[hh * DH_ + lane], 0.f);
            qg[(size_t)head * QH_P + i * 64 + lane] = f_to_f16bits(val);
            float s = val;
#pragma unroll
            for (int m = 1; m < 64; m <<= 1) s += __shfl_xor(s, m, 64);
            if (lane == 0) qsrow[i] = s;
        }
    }
}

// ---------------- Tversky attention: score = 2*sum(min(q,k)) / (qs+ks+2eps) ----------------
// No launch_bounds cap (round-5 lesson: (256,3) forced 88MB/dispatch of scratch spill).
// K consumed in two 4-chunk halves, half-loop NOT unrolled -> ~32 VGPR K-resident
// instead of 64, targeting <=170 VGPR so 3 waves/SIMD fit naturally (LDS caps 3 blocks/CU).
__global__ __launch_bounds__(256) void tversky_attn_kernel(const ushort* __restrict__ qg,
                                                           const ushort* __restrict__ kg,
                                                           const float* __restrict__ ksg,
                                                           const ushort* __restrict__ vgt,
                                                           const float* __restrict__ qsg,
                                                           __hip_bfloat16* __restrict__ ao,
                                                           int nrows) {
    __shared__ __align__(16) ushort kf[16384];   // 256 rows x 64 f16, chunk-swizzled
    __shared__ __align__(16) float ks_l[256];
    __shared__ __align__(16) ushort q_l[1024];   // [wave][4 rows][64] f16
    __shared__ __align__(16) ushort p_l[4096];   // [16 rows][256 j] bf16, swizzled
    __shared__ __align__(16) float den_l[16];

    const int tid = threadIdx.x, wv = tid >> 6, lane = tid & 63;
    const int quad = lane >> 4, l15 = lane & 15;
    const int ch = blockIdx.x, hh = blockIdx.y, bb = blockIdx.z;
    const int head = bb * NH_ + hh;

    {
        const ushort* kgh = kg + (size_t)head * KGP;
#pragma unroll
        for (int g = 0; g < 8; ++g) {
            int idx = g * 256 + tid;
            int row = idx >> 3, c = idx & 7;
            int sw = c ^ ((row >> 1) & 7);
            *(uint4*)&kf[row * 64 + sw * 8] = *(const uint4*)&kgh[idx * 8];
        }
        ks_l[tid] = ksg[(size_t)head * 256 + tid];
    }
    const int i0 = ch * 16 + wv * 4;
    if (lane < 32) {
        int r = lane >> 3, c = lane & 7;
        int i = i0 + r;
        uint4 qv = make_uint4(0, 0, 0, 0);
        if (i < nrows) qv = *(const uint4*)&qg[(size_t)head * QH_P + i * 64 + c * 8];
        *(uint4*)&q_l[wv * 256 + r * 64 + c * 8] = qv;
    }
    float qs_r[4];
#pragma unroll
    for (int r = 0; r < 4; ++r)
        qs_r[r] = (i0 + r < nrows) ? qsg[(size_t)head * 200 + i0 + r] : 0.f;
    __syncthreads();

#if HAS_FDOT2
    const f16x2_t one2 = __builtin_bit_cast(f16x2_t, 0x3C003C00u);
#endif
    float den_r[4] = {0.f, 0.f, 0.f, 0.f};
#pragma unroll
    for (int ph = 0; ph < 2; ++ph) {
        const int jb = ph * 128;
        const int r0 = (jb + 2 * lane) * 64;
        float acc0[4] = {0.f, 0.f, 0.f, 0.f};
        float acc1[4] = {0.f, 0.f, 0.f, 0.f};
        // two 4-chunk halves; half-loop kept as a real loop so only 8 uint4 of K
        // are register-resident at a time (full preload was 16 -> VGPR 172 -> 2 waves)
#pragma unroll 1
        for (int hf = 0; hf < 2; ++hf) {
            uint4 kreg0[4], kreg1[4];
#pragma unroll
            for (int c = 0; c < 4; ++c) {
                int sw = ((hf * 4 + c) ^ (lane & 7)) * 8;
                kreg0[c] = *(const uint4*)&kf[r0 + sw];
                kreg1[c] = *(const uint4*)&kf[r0 + 64 + sw];
            }
#pragma unroll
            for (int c = 0; c < 4; ++c) {
                int cc = hf * 4 + c;
                uint k0p[4] = {kreg0[c].x, kreg0[c].y, kreg0[c].z, kreg0[c].w};
                uint k1p[4] = {kreg1[c].x, kreg1[c].y, kreg1[c].z, kreg1[c].w};
#pragma unroll
                for (int r = 0; r < 4; ++r) {
                    uint4 qu = *(const uint4*)&q_l[wv * 256 + r * 64 + cc * 8];
                    uint qp[4] = {qu.x, qu.y, qu.z, qu.w};
#if HAS_FDOT2
#pragma unroll
                    for (int p = 0; p < 4; ++p) {
                        f16x2_t qq = u2h(qp[p]);
                        acc0[r] = __builtin_amdgcn_fdot2(min2(qq, u2h(k0p[p])), one2, acc0[r], false);
                        acc1[r] = __builtin_amdgcn_fdot2(min2(qq, u2h(k1p[p])), one2, acc1[r], false);
                    }
#else
                    f16x2_t m0 = min2(u2h(qp[0]), u2h(k0p[0]));
                    f16x2_t m1 = min2(u2h(qp[0]), u2h(k1p[0]));
#pragma unroll
                    for (int p = 1; p < 4; ++p) {
                        m0 = m0 + min2(u2h(qp[p]), u2h(k0p[p]));
                        m1 = m1 + min2(u2h(qp[p]), u2h(k1p[p]));
                    }
                    acc0[r] += (float)m0[0] + (float)m0[1];
                    acc1[r] += (float)m1[0] + (float)m1[1];
#endif
                }
            }
        }
        float2 ks2 = *(const float2*)&ks_l[jb + 2 * lane];
#pragma unroll
        for (int r = 0; r < 4; ++r) {
            float s0 = qs_r[r] + ks2.x, s1 = qs_r[r] + ks2.y;
            float e0 = __expf((2.f * acc0[r]) / (s0 + 2e-8f));
            float e1 = __expf((2.f * acc1[r]) / (s1 + 2e-8f));
            float sum = e0 + e1;
#pragma unroll
            for (int m = 1; m < 64; m <<= 1) sum += __shfl_xor(sum, m, 64);
            den_r[r] += sum;
            uint pw = (uint)f_to_bf16bits(e0) | ((uint)f_to_bf16bits(e1) << 16);
            int i = wv * 4 + r;
            *(uint*)&p_l[(i * 256 + jb + 2 * lane) ^ ((i & 7) * 8)] = pw;
        }
    }
    if (lane == 0) {
#pragma unroll
        for (int r = 0; r < 4; ++r) den_l[wv * 4 + r] = den_r[r];
    }
    __syncthreads();

    const ushort* vb = vgt + (size_t)head * KGP + (size_t)(16 * wv + l15) * 256;
    f32x4_t accv = {0.f, 0.f, 0.f, 0.f};
#pragma unroll
    for (int st = 0; st < 8; ++st) {
        bf16x8_t a = *(const bf16x8_t*)&p_l[(l15 * 256 + st * 32 + quad * 8) ^ ((l15 & 7) * 8)];
        bf16x8_t b = *(const bf16x8_t*)&vb[st * 32 + quad * 8];
        accv = __builtin_amdgcn_mfma_f32_16x16x32_bf16(a, b, accv, 0, 0, 0);
    }
    float4 dv = *(const float4*)&den_l[quad * 4];
    float dar[4] = {dv.x, dv.y, dv.z, dv.w};
#pragma unroll
    for (int t = 0; t < 4; ++t) {
        int ig = ch * 16 + quad * 4 + t;
        if (ig < nrows)
            ao[((size_t)(bb * nrows + ig)) * E_ + hh * DH_ + 16 * wv + l15] =
                __float2bfloat16(accv[t] / dar[t]);
    }
}

// ---------------- head: fused fc2-splitK reduce + final LN + classifier ----------------
__global__ __launch_bounds__(256) void head_ln_kernel(const float* __restrict__ hc,
                                                      const float* __restrict__ pc0,
                                                      const float* __restrict__ pc1,
                                                      const float* __restrict__ fb,
                                                      const float* __restrict__ lw,
                                                      const float* __restrict__ lb,
                                                      const float* __restrict__ hw,
                                                      const float* __restrict__ hb,
                                                      float* __restrict__ out) {
    int b = blockIdx.y;
    int tid = threadIdx.x;
    const float* xr0 = hc  + (size_t)b * E_;
    const float* pr0 = pc0 + (size_t)b * E_;
    const float* pr1 = pc1 + (size_t)b * E_;
    float v0 = xr0[tid]       + pr0[tid]       + pr1[tid]       + fb[tid];
    float v1 = xr0[tid + 256] + pr0[tid + 256] + pr1[tid + 256] + fb[tid + 256];
    float v2 = xr0[tid + 512] + pr0[tid + 512] + pr1[tid + 512] + fb[tid + 512];
    float s  = v0 + v1 + v2;
    float sq = v0 * v0 + v1 * v1 + v2 * v2;
#pragma unroll
    for (int m = 1; m < 64; m <<= 1) {
        s  += __shfl_xor(s, m, 64);
        sq += __shfl_xor(sq, m, 64);
    }
    __shared__ float ss[4], sqs[4];
    __shared__ float xr[E_];
    __shared__ float partial[4][64];
    int wave = tid >> 6, lane = tid & 63;
    if (lane == 0) { ss[wave] = s; sqs[wave] = sq; }
    __syncthreads();
    s  = ss[0] + ss[1] + ss[2] + ss[3];
    sq = sqs[0] + sqs[1] + sqs[2] + sqs[3];
    float mu   = s * (1.0f / 768.0f);
    float var  = sq * (1.0f / 768.0f) - mu * mu;
    float rstd = rsqrtf(var + 1e-5f);
    xr[tid]       = (v0 - mu) * rstd * lw[tid]       + lb[tid];
    xr[tid + 256] = (v1 - mu) * rstd * lw[tid + 256] + lb[tid + 256];
    xr[tid + 512] = (v2 - mu) * rstd * lw[tid + 512] + lb[tid + 512];
    __syncthreads();
    int nl = tid & 63, eq = tid >> 6;
    int n = blockIdx.x * 64 + nl;
    float acc = 0.f;
    if (n < OUT_) {
        int e0 = eq * 192;
        for (int e = e0; e < e0 + 192; ++e) acc += xr[e] * hw[(size_t)e * OUT_ + n];
    }
    partial[eq][nl] = acc;
    __syncthreads();
    if (eq == 0 && n < OUT_)
        out[(size_t)b * OUT_ + n] = partial[0][nl] + partial[1][nl] + partial[2][nl] + partial[3][nl] + hb[n];
}

extern "C" void kernel_launch(void* const* d_in, const int* in_sizes, int n_in,
                              void* d_out, int out_size, void* d_ws, size_t ws_size,
                              hipStream_t stream) {
    const float* x        = (const float*)d_in[0];
    const float* conv_w   = (const float*)d_in[1];
    const float* conv_b   = (const float*)d_in[2];
    const float* pos_e    = (const float*)d_in[3];
    const float* cls_t    = (const float*)d_in[4];
    const float* ln1_w    = (const float*)d_in[5];
    const float* ln1_b    = (const float*)d_in[6];
    const float* attn_w   = (const float*)d_in[7];
    const float* attn_b   = (const float*)d_in[8];
    const float* proj_w   = (const float*)d_in[9];
    const float* proj_b   = (const float*)d_in[10];
    const float* ln2_w    = (const float*)d_in[11];
    const float* ln2_b    = (const float*)d_in[12];
    const float* fc1_w    = (const float*)d_in[13];
    const float* fc1_b    = (const float*)d_in[14];
    const float* fc2_w    = (const float*)d_in[15];
    const float* fc2_b    = (const float*)d_in[16];
    const float* lnf_w    = (const float*)d_in[17];
    const float* lnf_b    = (const float*)d_in[18];
    const float* head_w   = (const float*)d_in[19];
    const float* head_b   = (const float*)d_in[20];
    float* out = (float*)d_out;

    // workspace layout
    float* h       = (float*)d_ws;                 // 605184
    float* part0q  = h + 605184;                   // 2x1815552 (QKV parts, contiguous)
    float* part1q  = part0q + 1815552;
    float* part    = part1q + 1815552;             // 2x605184 (patch/proj/fc2 parts)
    float* hc      = part + 3631104;               // 3072
    float* partc   = hc + 3072;                    // 6144
    float* ksg     = partc + 6144;                 // 12288
    float* qsg     = ksg + 12288;                  // 9600
    __hip_bfloat16* lnb  = (__hip_bfloat16*)(qsg + 9600);   // 605184
    __hip_bfloat16* ao   = lnb + 605184;                    // 605184
    __hip_bfloat16* hid  = ao + 605184;                     // 2420736
    __hip_bfloat16* aim  = hid + 2420736;                   // 602112
    __hip_bfloat16* wt   = aim + 602112;                    // 14745600
    ushort* kg  = (ushort*)(wt + 14745600);                 // 786432
    ushort* vgt = kg + 786432;                              // 786432
    ushort* qg  = vgt + 786432;                             // 605184
    __hip_bfloat16* lnb4 = (__hip_bfloat16*)(qg + 605184);  // 3072
    __hip_bfloat16* hid4 = lnb4 + 3072;                     // 12288

    // ---- prologue ----
    prep_all_kernel<<<4620, 256, 0, stream>>>(x, aim, attn_w, proj_w, fc1_w, fc2_w, conv_w, wt);
    {
        dim3 grid(E_ / 64, 13, 2);
        gemm_mfma_kernel<<<grid, 256, 0, stream>>>(aim, wt + WT_CONV, nullptr, nullptr, nullptr,
                                                   nullptr, part, 784, E_, E_, 0, 2, 0, E_, 0);
    }
    embed_ln_kernel<<<ROWS_, 256, 0, stream>>>(part, part + 602112, conv_b,
                                               pos_e, cls_t, ln1_w, ln1_b, h, lnb);

    // ---- layer 0 (full 788 rows) ----
    {
        const __hip_bfloat16* wl = wt + WT_LBASE;
        {
            dim3 grid((3 * E_) / 64, 13, 2);
            gemm_mfma_kernel<<<grid, 256, 0, stream>>>(lnb, wl + WT_QKV, nullptr, nullptr,
                                                       nullptr, nullptr, part0q,
                                                       ROWS_, 3 * E_, E_, 0, 2, 0, 3 * E_, 0);
        }
        attn_prep_kernel<<<dim3(NH_, B_, 6), 256, 0, stream>>>(
            part0q, part1q, attn_b, kg, ksg, qg, vgt, qsg, S_, lnb, attn_w);
        tversky_attn_kernel<<<dim3(13, NH_, B_), 256, 0, stream>>>(
            qg, kg, ksg, vgt, qsg, ao, S_);
        {
            dim3 grid(E_ / 64, 13, 2);
            gemm_mfma_kernel<<<grid, 256, 0, stream>>>(ao, wl + WT_PROJ, nullptr, nullptr, nullptr,
                                                       nullptr, part, ROWS_, E_, E_, 0, 2, 0, E_, 0);
        }
        reduce_ln_kernel<<<ROWS_, 256, 0, stream>>>(part, 2, 605184, proj_b,
                                                    h, ln2_w, ln2_b, lnb);
        {
            dim3 grid(DFF_ / 64, 13);
            gemm_mfma_kernel<<<grid, 256, 0, stream>>>(lnb, wl + WT_FC1, fc1_b,
                                                       nullptr, nullptr, hid, nullptr,
                                                       ROWS_, DFF_, E_, 1, 1, 0, DFF_, 0);
        }
        {
            dim3 grid(E_ / 64, 13, 2);
            gemm_mfma_kernel<<<grid, 256, 0, stream>>>(hid, wl + WT_FC2, nullptr, nullptr, nullptr,
                                                       nullptr, part, ROWS_, E_, DFF_, 0, 2, 0, E_, 0);
        }
        reduce_ln_kernel<<<ROWS_, 256, 0, stream>>>(part, 2, 605184, fc2_b,
                                                    h, ln1_w + E_, ln1_b + E_, lnb);
    }

    // ---- layer 1: only CLS rows (4) needed downstream; QKV computes K,V only ----
    {
        const __hip_bfloat16* wl = wt + WT_LBASE + WT_LSTRIDE;
        {
            // N=1536 (K,V cols 768..2304); WT offset skips Q rows; partials at n-offset 768
            dim3 grid(1536 / 64, 13, 2);
            gemm_mfma_kernel<<<grid, 256, 0, stream>>>(lnb, wl + WT_QKV + 768 * E_, nullptr, nullptr,
                                                       nullptr, nullptr, part0q,
                                                       ROWS_, 1536, E_, 0, 2, 0, 3 * E_, 768);
        }
        attn_prep_kernel<<<dim3(NH_, B_, 6), 256, 0, stream>>>(
            part0q, part1q, attn_b + 3 * E_, kg, ksg, qg, vgt, qsg, 1,
            lnb, attn_w + (size_t)E_ * 3 * E_);
        tversky_attn_kernel<<<dim3(1, NH_, B_), 256, 0, stream>>>(
            qg, kg, ksg, vgt, qsg, ao, 1);
        {
            dim3 grid(E_ / 64, 1, 1);
            gemm_mfma_kernel<<<grid, 256, 0, stream>>>(ao, wl + WT_PROJ, proj_b + E_, h,
                                                       hc, nullptr, nullptr,
                                                       4, E_, E_, 0, 1, S_ * E_, E_, 0);
        }
        layernorm_kernel<<<4, 256, 0, stream>>>(hc, ln2_w + E_, ln2_b + E_, lnb4);
        {
            dim3 grid(DFF_ / 64, 1, 1);
            gemm_mfma_kernel<<<grid, 256, 0, stream>>>(lnb4, wl + WT_FC1, fc1_b + DFF_,
                                                       nullptr, nullptr, hid4, nullptr,
                                                       4, DFF_, E_, 1, 1, 0, DFF_, 0);
        }
        {
            dim3 grid(E_ / 64, 1, 2);
            gemm_mfma_kernel<<<grid, 256, 0, stream>>>(hid4, wl + WT_FC2, nullptr, nullptr, nullptr,
                                                       nullptr, partc, 4, E_, DFF_, 0, 2, 0, E_, 0);
        }
    }

    {
        dim3 grid((OUT_ + 63) / 64, B_);
        head_ln_kernel<<<grid, 256, 0, stream>>>(hc, partc, partc + 3072, fc2_b + E_,
                                                 lnf_w, lnf_b, head_w, head_b, out);
    }
}

// Round 7
// 317.865 us; speedup vs baseline: 1.1834x; 1.0447x over previous
//
#include <hip/hip_runtime.h>
#include <hip/hip_bf16.h>
#include <math.h>

// Shapes
#define B_  4
#define E_  768
#define NH_ 12
#define DH_ 64
#define DFF_ 3072
#define OUT_ 1000
#define S_  197
#define ROWS_ 788          // B_*S_
#define QH_P 12608         // 197*64 per-head q pitch
#define KGP  16384         // 256*64 per-head k / v^T pitch

typedef __bf16 bf16x8_t __attribute__((ext_vector_type(8)));
typedef float f32x4_t __attribute__((ext_vector_type(4)));
typedef _Float16 f16x2_t __attribute__((ext_vector_type(2)));

#define HAS_FDOT2 __has_builtin(__builtin_amdgcn_fdot2)

__device__ __forceinline__ float gelu_f(float x) {
    float x3 = x * x * x;
    return 0.5f * x * (1.0f + tanhf(0.7978845608028654f * (x + 0.044715f * x3)));
}
__device__ __forceinline__ ushort f_to_bf16bits(float f) {
    __hip_bfloat16 b = __float2bfloat16(f);
    return *(ushort*)&b;
}
__device__ __forceinline__ ushort f_to_f16bits(float f) {
    _Float16 h = (_Float16)f;
    return __builtin_bit_cast(ushort, h);
}
__device__ __forceinline__ f16x2_t u2h(uint u) { return __builtin_bit_cast(f16x2_t, u); }
__device__ __forceinline__ f16x2_t min2(f16x2_t a, f16x2_t b) {
    return __builtin_elementwise_min(a, b);
}

// ---------------- merged prologue prep: im2col + reg-transpose weights + conv cvt + vgt pad zero ----------------
#define WT_CONV   0
#define WT_LBASE  589824
#define WT_LSTRIDE 7077888
#define WT_QKV    0
#define WT_PROJ   1769472
#define WT_FC1    2359296
#define WT_FC2    4718592
__global__ __launch_bounds__(256) void prep_all_kernel(const float* __restrict__ x,
                                                       __hip_bfloat16* __restrict__ aim,
                                                       const float* __restrict__ attn_w,
                                                       const float* __restrict__ proj_w,
                                                       const float* __restrict__ fc1_w,
                                                       const float* __restrict__ fc2_w,
                                                       const float* __restrict__ conv_w,
                                                       __hip_bfloat16* __restrict__ wt,
                                                       ushort* __restrict__ vgt) {
    int bid = blockIdx.x;
    if (bid < 588) {                        // im2col, 4 elems/thread
        int id = bid * 256 + threadIdx.x;   // 0..150527
        int row = id / 192, k4 = (id - row * 192) * 4;
        int b = row / 196, pr = row - b * 196;
        int hp = pr / 14, wp = pr - hp * 14;
        int c = k4 >> 8, rem = k4 & 255, p = rem >> 4, q = rem & 15;
        float4 v = *(const float4*)&x[(((size_t)(b * 3 + c) * 224) + hp * 16 + p) * 224 + wp * 16 + q];
        ushort4 o = make_ushort4(f_to_bf16bits(v.x), f_to_bf16bits(v.y), f_to_bf16bits(v.z), f_to_bf16bits(v.w));
        *(ushort4*)((ushort*)aim + (size_t)row * 768 + k4) = o;
        return;
    }
    int id = bid - 588;
    if (id < 3456) {                        // 64x64 register transpose tiles
        int l = id / 1728, r = id - l * 1728;
        const float* src;
        __hip_bfloat16* dst;
        int K, N, tile;
        size_t lbase = WT_LBASE + (size_t)l * WT_LSTRIDE;
        if (r < 432)       { src = attn_w + (size_t)l * E_ * 3 * E_; dst = wt + lbase + WT_QKV;  K = E_;   N = 3 * E_; tile = r; }
        else if (r < 576)  { src = proj_w + (size_t)l * E_ * E_;     dst = wt + lbase + WT_PROJ; K = E_;   N = E_;     tile = r - 432; }
        else if (r < 1152) { src = fc1_w + (size_t)l * E_ * DFF_;    dst = wt + lbase + WT_FC1;  K = E_;   N = DFF_;   tile = r - 576; }
        else               { src = fc2_w + (size_t)l * DFF_ * E_;    dst = wt + lbase + WT_FC2;  K = DFF_; N = E_;     tile = r - 1152; }
        int ntn = N >> 6;
        int kb = (tile / ntn) * 64, nb = (tile % ntn) * 64;
        int kq = (threadIdx.x & 15) * 4, nq = (threadIdx.x >> 4) * 4;
        const float* s0 = src + (size_t)(kb + kq) * N + nb + nq;
        float4 v0 = *(const float4*)(s0);
        float4 v1 = *(const float4*)(s0 + N);
        float4 v2 = *(const float4*)(s0 + 2 * N);
        float4 v3 = *(const float4*)(s0 + 3 * N);
        __hip_bfloat16* d0 = dst + (size_t)(nb + nq) * K + kb + kq;
        *(ushort4*)(d0)         = make_ushort4(f_to_bf16bits(v0.x), f_to_bf16bits(v1.x), f_to_bf16bits(v2.x), f_to_bf16bits(v3.x));
        *(ushort4*)(d0 + K)     = make_ushort4(f_to_bf16bits(v0.y), f_to_bf16bits(v1.y), f_to_bf16bits(v2.y), f_to_bf16bits(v3.y));
        *(ushort4*)(d0 + 2 * K) = make_ushort4(f_to_bf16bits(v0.z), f_to_bf16bits(v1.z), f_to_bf16bits(v2.z), f_to_bf16bits(v3.z));
        *(ushort4*)(d0 + 3 * K) = make_ushort4(f_to_bf16bits(v0.w), f_to_bf16bits(v1.w), f_to_bf16bits(v2.w), f_to_bf16bits(v3.w));
        return;
    }
    id -= 3456;
    if (id < 576) {                          // conv cvt (already [N,K]), 4/thread
        int off = (id * 256 + threadIdx.x) * 4;
        float4 v = *(const float4*)&conv_w[off];
        ushort4 o = make_ushort4(f_to_bf16bits(v.x), f_to_bf16bits(v.y), f_to_bf16bits(v.z), f_to_bf16bits(v.w));
        *(ushort4*)((ushort*)wt + WT_CONV + off) = o;
        return;
    }
    id -= 576;
    {                                        // zero vgt (48*16384 ushorts) so pad j-cols stay 0 forever
        int off = (id * 256 + threadIdx.x) * 4;
        *(ushort4*)&vgt[off] = make_ushort4(0, 0, 0, 0);
    }
}

// ---------------- MFMA GEMM 64x64: LDS dbuf, prefetch depth 2, split-K, partial n-offset ----------------
#define BK 64
#define AP 72
__global__ __launch_bounds__(256) void gemm_mfma_kernel(const __hip_bfloat16* __restrict__ A,
                                                        const __hip_bfloat16* __restrict__ WT,
                                                        const float* __restrict__ bias,
                                                        const float* __restrict__ res,
                                                        float* __restrict__ Cf,
                                                        __hip_bfloat16* __restrict__ Cb,
                                                        float* __restrict__ partbase,
                                                        int M, int N, int K, int act, int KS,
                                                        int res_pitch, int pn, int nofs) {
    __shared__ __align__(16) ushort Asb[2][64 * AP];
    __shared__ __align__(16) ushort Bsb[2][64 * AP];
    const int tid = threadIdx.x;
    const int wave = tid >> 6, lane = tid & 63;
    const int quad = lane >> 4, l15 = lane & 15;
    const int wm = wave >> 1, wn = wave & 1;
    const int m0 = blockIdx.y * 64, n0 = blockIdx.x * 64;

    const int Kc   = K / KS;
    const int kbeg = blockIdx.z * Kc;
    const int n_it = Kc / BK;

    f32x4_t acc[2][2] = {};

    const int c0r = tid >> 3,         c0o = (tid & 7) * 8;
    const int c1r = (tid + 256) >> 3, c1o = c0o;

    uint4 pa0, pa1, pb0, pb1;
    auto load_tile = [&](int kk) {
        pa0 = make_uint4(0, 0, 0, 0);
        pa1 = pa0;
        int gm = m0 + c0r;
        if (gm < M) pa0 = *(const uint4*)&A[(size_t)gm * K + kk + c0o];
        gm = m0 + c1r;
        if (gm < M) pa1 = *(const uint4*)&A[(size_t)gm * K + kk + c1o];
        pb0 = *(const uint4*)&WT[(size_t)(n0 + c0r) * K + kk + c0o];
        pb1 = *(const uint4*)&WT[(size_t)(n0 + c1r) * K + kk + c1o];
    };
    auto store_tile = [&](int buf) {
        *(uint4*)&Asb[buf][c0r * AP + c0o] = pa0;
        *(uint4*)&Asb[buf][c1r * AP + c1o] = pa1;
        *(uint4*)&Bsb[buf][c0r * AP + c0o] = pb0;
        *(uint4*)&Bsb[buf][c1r * AP + c1o] = pb1;
    };

    load_tile(kbeg);
    store_tile(0);
    if (n_it > 1) load_tile(kbeg + BK);
    __syncthreads();

    for (int it = 0; it < n_it; ++it) {
        const int cur = it & 1, nxt = cur ^ 1;
        if (it + 1 < n_it) {
            store_tile(nxt);
            if (it + 2 < n_it) load_tile(kbeg + (it + 2) * BK);
        }
        const ushort* As = Asb[cur];
        const ushort* Bs = Bsb[cur];
#pragma unroll
        for (int ks = 0; ks < BK; ks += 32) {
            bf16x8_t a0 = *(const bf16x8_t*)&As[(32 * wm + l15) * AP + ks + 8 * quad];
            bf16x8_t a1 = *(const bf16x8_t*)&As[(32 * wm + 16 + l15) * AP + ks + 8 * quad];
            bf16x8_t b0 = *(const bf16x8_t*)&Bs[(32 * wn + l15) * AP + ks + 8 * quad];
            bf16x8_t b1 = *(const bf16x8_t*)&Bs[(32 * wn + 16 + l15) * AP + ks + 8 * quad];
            acc[0][0] = __builtin_amdgcn_mfma_f32_16x16x32_bf16(a0, b0, acc[0][0], 0, 0, 0);
            acc[0][1] = __builtin_amdgcn_mfma_f32_16x16x32_bf16(a0, b1, acc[0][1], 0, 0, 0);
            acc[1][0] = __builtin_amdgcn_mfma_f32_16x16x32_bf16(a1, b0, acc[1][0], 0, 0, 0);
            acc[1][1] = __builtin_amdgcn_mfma_f32_16x16x32_bf16(a1, b1, acc[1][1], 0, 0, 0);
        }
        __syncthreads();
    }

    if (partbase) {
        float* P = partbase + (size_t)blockIdx.z * M * pn;
#pragma unroll
        for (int mi = 0; mi < 2; ++mi)
#pragma unroll
            for (int ni = 0; ni < 2; ++ni) {
                int gn = n0 + 32 * wn + 16 * ni + l15;
#pragma unroll
                for (int r = 0; r < 4; ++r) {
                    int gm = m0 + 32 * wm + 16 * mi + quad * 4 + r;
                    if (gm < M) P[(size_t)gm * pn + nofs + gn] = acc[mi][ni][r];
                }
            }
        return;
    }

#pragma unroll
    for (int mi = 0; mi < 2; ++mi)
#pragma unroll
        for (int ni = 0; ni < 2; ++ni) {
            int gn = n0 + 32 * wn + 16 * ni + l15;
#pragma unroll
            for (int r = 0; r < 4; ++r) {
                int gm = m0 + 32 * wm + 16 * mi + quad * 4 + r;
                if (gm < M) {
                    float v = acc[mi][ni][r] + bias[gn];
                    if (act == 1) v = gelu_f(v);
                    if (res) v += res[(size_t)gm * res_pitch + gn];
                    if (Cf) Cf[(size_t)gm * N + gn] = v;
                    else    Cb[(size_t)gm * N + gn] = __float2bfloat16(v);
                }
            }
        }
}

// ---------------- QKV GEMM with fused attention-prep epilogue ----------------
// Each 64-col tile is exactly one head's d-range (region/head block-uniform).
// region 0 (Q): relu -> qg f16 [head][i*64+d] + qs row-sums
// region 1 (K): relu -> kg f16 [head][j*64+d] + ks row-sums
// region 2 (V): -> vgt bf16 [head][d*256+j] (transposed scatter; pad j stays 0 from prep)
__global__ __launch_bounds__(256) void gemm_qkv_kernel(const __hip_bfloat16* __restrict__ A,
                                                       const __hip_bfloat16* __restrict__ WT,
                                                       const float* __restrict__ ab,
                                                       ushort* __restrict__ qg,
                                                       float* __restrict__ qsg,
                                                       ushort* __restrict__ kg,
                                                       float* __restrict__ ksg,
                                                       ushort* __restrict__ vgt,
                                                       int ncol0) {
    __shared__ __align__(16) ushort Asb[2][64 * AP];
    __shared__ __align__(16) ushort Bsb[2][64 * AP];
    __shared__ float rs[2][64];
    const int tid = threadIdx.x;
    const int wave = tid >> 6, lane = tid & 63;
    const int quad = lane >> 4, l15 = lane & 15;
    const int wm = wave >> 1, wn = wave & 1;
    const int m0 = blockIdx.y * 64;
    const int n0g = ncol0 + blockIdx.x * 64;

    f32x4_t acc[2][2] = {};

    const int c0r = tid >> 3,         c0o = (tid & 7) * 8;
    const int c1r = (tid + 256) >> 3, c1o = c0o;

    uint4 pa0, pa1, pb0, pb1;
    auto load_tile = [&](int kk) {
        pa0 = make_uint4(0, 0, 0, 0);
        pa1 = pa0;
        int gm = m0 + c0r;
        if (gm < ROWS_) pa0 = *(const uint4*)&A[(size_t)gm * E_ + kk + c0o];
        gm = m0 + c1r;
        if (gm < ROWS_) pa1 = *(const uint4*)&A[(size_t)gm * E_ + kk + c1o];
        pb0 = *(const uint4*)&WT[(size_t)(n0g + c0r) * E_ + kk + c0o];
        pb1 = *(const uint4*)&WT[(size_t)(n0g + c1r) * E_ + kk + c1o];
    };
    auto store_tile = [&](int buf) {
        *(uint4*)&Asb[buf][c0r * AP + c0o] = pa0;
        *(uint4*)&Asb[buf][c1r * AP + c1o] = pa1;
        *(uint4*)&Bsb[buf][c0r * AP + c0o] = pb0;
        *(uint4*)&Bsb[buf][c1r * AP + c1o] = pb1;
    };

    load_tile(0);
    store_tile(0);
    load_tile(BK);
    __syncthreads();

    const int n_it = E_ / BK;   // 12
    for (int it = 0; it < n_it; ++it) {
        const int cur = it & 1, nxt = cur ^ 1;
        if (it + 1 < n_it) {
            store_tile(nxt);
            if (it + 2 < n_it) load_tile((it + 2) * BK);
        }
        const ushort* As = Asb[cur];
        const ushort* Bs = Bsb[cur];
#pragma unroll
        for (int ks = 0; ks < BK; ks += 32) {
            bf16x8_t a0 = *(const bf16x8_t*)&As[(32 * wm + l15) * AP + ks + 8 * quad];
            bf16x8_t a1 = *(const bf16x8_t*)&As[(32 * wm + 16 + l15) * AP + ks + 8 * quad];
            bf16x8_t b0 = *(const bf16x8_t*)&Bs[(32 * wn + l15) * AP + ks + 8 * quad];
            bf16x8_t b1 = *(const bf16x8_t*)&Bs[(32 * wn + 16 + l15) * AP + ks + 8 * quad];
            acc[0][0] = __builtin_amdgcn_mfma_f32_16x16x32_bf16(a0, b0, acc[0][0], 0, 0, 0);
            acc[0][1] = __builtin_amdgcn_mfma_f32_16x16x32_bf16(a0, b1, acc[0][1], 0, 0, 0);
            acc[1][0] = __builtin_amdgcn_mfma_f32_16x16x32_bf16(a1, b0, acc[1][0], 0, 0, 0);
            acc[1][1] = __builtin_amdgcn_mfma_f32_16x16x32_bf16(a1, b1, acc[1][1], 0, 0, 0);
        }
        __syncthreads();
    }

    const int region = n0g / 768;            // 0=Q, 1=K, 2=V (block-uniform)
    const int hh = (n0g >> 6) % 12;          // head within region (block-uniform)
    const float bias0 = ab[n0g + 32 * wn + l15];
    const float bias1 = ab[n0g + 32 * wn + 16 + l15];

    float rsum[2][4] = {};
#pragma unroll
    for (int mi = 0; mi < 2; ++mi)
#pragma unroll
        for (int ni = 0; ni < 2; ++ni) {
            const int d = 32 * wn + 16 * ni + l15;
#pragma unroll
            for (int r = 0; r < 4; ++r) {
                int gm = m0 + 32 * wm + 16 * mi + quad * 4 + r;
                if (gm < ROWS_) {
                    float v = acc[mi][ni][r] + (ni ? bias1 : bias0);
                    int b = gm / S_, j = gm - b * S_;
                    int head = b * NH_ + hh;
                    if (region == 0) {
                        v = fmaxf(v, 0.f);
                        qg[(size_t)head * QH_P + j * 64 + d] = f_to_f16bits(v);
                        rsum[mi][r] += v;
                    } else if (region == 1) {
                        v = fmaxf(v, 0.f);
                        kg[(size_t)head * KGP + j * 64 + d] = f_to_f16bits(v);
                        rsum[mi][r] += v;
                    } else {
                        vgt[(size_t)head * KGP + d * 256 + j] = f_to_bf16bits(v);
                    }
                }
            }
        }

    if (region < 2) {     // row-sums: 2 ni (done) x 16 l15 (shfl) x 2 wn (LDS)
#pragma unroll
        for (int mi = 0; mi < 2; ++mi)
#pragma unroll
            for (int r = 0; r < 4; ++r) {
                float s = rsum[mi][r];
                s += __shfl_xor(s, 1, 64);
                s += __shfl_xor(s, 2, 64);
                s += __shfl_xor(s, 4, 64);
                s += __shfl_xor(s, 8, 64);
                rsum[mi][r] = s;
            }
        if (l15 == 0) {
#pragma unroll
            for (int mi = 0; mi < 2; ++mi)
#pragma unroll
                for (int r = 0; r < 4; ++r)
                    rs[wn][32 * wm + 16 * mi + quad * 4 + r] = rsum[mi][r];
        }
        __syncthreads();
        if (tid < 64) {
            int gm = m0 + tid;
            if (gm < ROWS_) {
                int b = gm / S_, j = gm - b * S_;
                int head = b * NH_ + hh;
                float s = rs[0][tid] + rs[1][tid];
                if (region == 0) qsg[(size_t)head * 200 + j] = s;
                else             ksg[(size_t)head * 256 + j] = s;
            }
        }
    }
}

// ---------------- embed (split-K patch parts + conv_b + pe) + cls + LN1(l=0) fused ----------------
__global__ __launch_bounds__(256) void embed_ln_kernel(const float* __restrict__ p0,
                                                       const float* __restrict__ p1,
                                                       const float* __restrict__ cb,
                                                       const float* __restrict__ pe,
                                                       const float* __restrict__ ct,
                                                       const float* __restrict__ lw,
                                                       const float* __restrict__ lb,
                                                       float* __restrict__ h,
                                                       __hip_bfloat16* __restrict__ y) {
    int row = blockIdx.x, tid = threadIdx.x;
    int b = row / S_, s = row - b * S_;
    float v[3];
#pragma unroll
    for (int c = 0; c < 3; ++c) {
        int e = tid + c * 256;
        float t;
        if (s == 0) t = ct[e];
        else {
            int pr = s - 1;
            size_t gi = (size_t)(b * 196 + pr) * E_ + e;
            t = p0[gi] + p1[gi] + cb[e] + pe[(size_t)pr * E_ + e];
        }
        h[(size_t)row * E_ + e] = t;
        v[c] = t;
    }
    float sm = v[0] + v[1] + v[2];
    float sq = v[0] * v[0] + v[1] * v[1] + v[2] * v[2];
#pragma unroll
    for (int m = 1; m < 64; m <<= 1) {
        sm += __shfl_xor(sm, m, 64);
        sq += __shfl_xor(sq, m, 64);
    }
    __shared__ float ss[4], sqs[4];
    int wave = tid >> 6, lane = tid & 63;
    if (lane == 0) { ss[wave] = sm; sqs[wave] = sq; }
    __syncthreads();
    sm = ss[0] + ss[1] + ss[2] + ss[3];
    sq = sqs[0] + sqs[1] + sqs[2] + sqs[3];
    float mu   = sm * (1.0f / 768.0f);
    float var  = sq * (1.0f / 768.0f) - mu * mu;
    float rstd = rsqrtf(var + 1e-5f);
    __hip_bfloat16* yr = y + (size_t)row * E_;
#pragma unroll
    for (int c = 0; c < 3; ++c) {
        int e = tid + c * 256;
        yr[e] = __float2bfloat16((v[c] - mu) * rstd * lw[e] + lb[e]);
    }
}

// ---------------- LayerNorm (fp32 in, bf16 out) ----------------
__global__ __launch_bounds__(256) void layernorm_kernel(const float* __restrict__ x,
                                                        const float* __restrict__ w,
                                                        const float* __restrict__ b,
                                                        __hip_bfloat16* __restrict__ y) {
    int row = blockIdx.x;
    const float* xr = x + (size_t)row * E_;
    int tid = threadIdx.x;
    float v0 = xr[tid], v1 = xr[tid + 256], v2 = xr[tid + 512];
    float s  = v0 + v1 + v2;
    float sq = v0 * v0 + v1 * v1 + v2 * v2;
#pragma unroll
    for (int m = 1; m < 64; m <<= 1) {
        s  += __shfl_xor(s, m, 64);
        sq += __shfl_xor(sq, m, 64);
    }
    __shared__ float ss[4], sqs[4];
    int wave = tid >> 6, lane = tid & 63;
    if (lane == 0) { ss[wave] = s; sqs[wave] = sq; }
    __syncthreads();
    s  = ss[0] + ss[1] + ss[2] + ss[3];
    sq = sqs[0] + sqs[1] + sqs[2] + sqs[3];
    float mu   = s * (1.0f / 768.0f);
    float var  = sq * (1.0f / 768.0f) - mu * mu;
    float rstd = rsqrtf(var + 1e-5f);
    __hip_bfloat16* yr = y + (size_t)row * E_;
    yr[tid]       = __float2bfloat16((v0 - mu) * rstd * w[tid]       + b[tid]);
    yr[tid + 256] = __float2bfloat16((v1 - mu) * rstd * w[tid + 256] + b[tid + 256]);
    yr[tid + 512] = __float2bfloat16((v2 - mu) * rstd * w[tid + 512] + b[tid + 512]);
}

// ---------------- fused split-K(np) reduce + bias + residual + LayerNorm ----------------
__global__ __launch_bounds__(256) void reduce_ln_kernel(const float* __restrict__ parts,
                                                        int np, size_t pstride,
                                                        const float* __restrict__ bias,
                                                        float* __restrict__ h,
                                                        const float* __restrict__ lw,
                                                        const float* __restrict__ lb,
                                                        __hip_bfloat16* __restrict__ y) {
    int row = blockIdx.x, tid = threadIdx.x;
    float v[3];
#pragma unroll
    for (int c = 0; c < 3; ++c) {
        int e = tid + c * 256;
        size_t gi = (size_t)row * E_ + e;
        float t = bias[e] + h[gi];
        for (int z = 0; z < np; ++z) t += parts[z * pstride + gi];
        h[gi] = t;
        v[c] = t;
    }
    float s  = v[0] + v[1] + v[2];
    float sq = v[0] * v[0] + v[1] * v[1] + v[2] * v[2];
#pragma unroll
    for (int m = 1; m < 64; m <<= 1) {
        s  += __shfl_xor(s, m, 64);
        sq += __shfl_xor(sq, m, 64);
    }
    __shared__ float ss[4], sqs[4];
    int wave = tid >> 6, lane = tid & 63;
    if (lane == 0) { ss[wave] = s; sqs[wave] = sq; }
    __syncthreads();
    s  = ss[0] + ss[1] + ss[2] + ss[3];
    sq = sqs[0] + sqs[1] + sqs[2] + sqs[3];
    float mu   = s * (1.0f / 768.0f);
    float var  = sq * (1.0f / 768.0f) - mu * mu;
    float rstd = rsqrtf(var + 1e-5f);
    __hip_bfloat16* yr = y + (size_t)row * E_;
#pragma unroll
    for (int c = 0; c < 3; ++c) {
        int e = tid + c * 256;
        yr[e] = __float2bfloat16((v[c] - mu) * rstd * lw[e] + lb[e]);
    }
}

// ---------------- layer-1 CLS-row Q matvec (fp32 weights) ----------------
__global__ __launch_bounds__(256) void cls_q_kernel(const __hip_bfloat16* __restrict__ xin,
                                                    const float* __restrict__ wraw,
                                                    const float* __restrict__ ab,
                                                    ushort* __restrict__ qg,
                                                    float* __restrict__ qsg) {
    const int tid = threadIdx.x, lane = tid & 63, wv = tid >> 6;
    const int hh = blockIdx.x, bb = blockIdx.y;
    const int head = bb * NH_ + hh;
    __shared__ float sacc[4][64];
    const __hip_bfloat16* xr = xin + (size_t)(bb * S_) * E_;
    const float* wcol = wraw + hh * DH_;
    float acc = 0.f;
    const int k0 = wv * 192;
#pragma unroll 4
    for (int k = k0; k < k0 + 192; ++k)
        acc += __bfloat162float(xr[k]) * wcol[(size_t)k * (3 * E_) + lane];
    sacc[wv][lane] = acc;
    __syncthreads();
    if (tid < 64) {
        float q = sacc[0][tid] + sacc[1][tid] + sacc[2][tid] + sacc[3][tid] + ab[hh * DH_ + tid];
        q = fmaxf(q, 0.f);
        qg[(size_t)head * QH_P + tid] = f_to_f16bits(q);
        float s = q;
#pragma unroll
        for (int m = 1; m < 64; m <<= 1) s += __shfl_xor(s, m, 64);
        if (tid == 0) qsg[(size_t)head * 200] = s;
    }
}

// ---------------- Tversky attention: score = 2*sum(min(q,k)) / (qs+ks+2eps) ----------------
// Pad rows j>=197 synthesized at LDS-stage time (k=-64 f16 = 0xD400, ks=0); kg/ksg hold
// only real rows. K consumed in two 4-chunk halves (round-6 non-spilling structure).
__global__ __launch_bounds__(256) void tversky_attn_kernel(const ushort* __restrict__ qg,
                                                           const ushort* __restrict__ kg,
                                                           const float* __restrict__ ksg,
                                                           const ushort* __restrict__ vgt,
                                                           const float* __restrict__ qsg,
                                                           __hip_bfloat16* __restrict__ ao,
                                                           int nrows) {
    __shared__ __align__(16) ushort kf[16384];   // 256 rows x 64 f16, chunk-swizzled
    __shared__ __align__(16) float ks_l[256];
    __shared__ __align__(16) ushort q_l[1024];   // [wave][4 rows][64] f16
    __shared__ __align__(16) ushort p_l[4096];   // [16 rows][256 j] bf16, swizzled
    __shared__ __align__(16) float den_l[16];

    const int tid = threadIdx.x, wv = tid >> 6, lane = tid & 63;
    const int quad = lane >> 4, l15 = lane & 15;
    const int ch = blockIdx.x, hh = blockIdx.y, bb = blockIdx.z;
    const int head = bb * NH_ + hh;

    {
        const ushort* kgh = kg + (size_t)head * KGP;
#pragma unroll
        for (int g = 0; g < 8; ++g) {
            int idx = g * 256 + tid;
            int row = idx >> 3, c = idx & 7;
            int sw = c ^ ((row >> 1) & 7);
            uint4 kv;
            if (row < S_) kv = *(const uint4*)&kgh[idx * 8];
            else kv = make_uint4(0xD400D400u, 0xD400D400u, 0xD400D400u, 0xD400D400u);
            *(uint4*)&kf[row * 64 + sw * 8] = kv;
        }
        ks_l[tid] = (tid < S_) ? ksg[(size_t)head * 256 + tid] : 0.f;
    }
    const int i0 = ch * 16 + wv * 4;
    if (lane < 32) {
        int r = lane >> 3, c = lane & 7;
        int i = i0 + r;
        uint4 qv = make_uint4(0, 0, 0, 0);
        if (i < nrows) qv = *(const uint4*)&qg[(size_t)head * QH_P + i * 64 + c * 8];
        *(uint4*)&q_l[wv * 256 + r * 64 + c * 8] = qv;
    }
    float qs_r[4];
#pragma unroll
    for (int r = 0; r < 4; ++r)
        qs_r[r] = (i0 + r < nrows) ? qsg[(size_t)head * 200 + i0 + r] : 0.f;
    __syncthreads();

#if HAS_FDOT2
    const f16x2_t one2 = __builtin_bit_cast(f16x2_t, 0x3C003C00u);
#endif
    float den_r[4] = {0.f, 0.f, 0.f, 0.f};
#pragma unroll
    for (int ph = 0; ph < 2; ++ph) {
        const int jb = ph * 128;
        const int r0 = (jb + 2 * lane) * 64;
        float acc0[4] = {0.f, 0.f, 0.f, 0.f};
        float acc1[4] = {0.f, 0.f, 0.f, 0.f};
#pragma unroll 1
        for (int hf = 0; hf < 2; ++hf) {
            uint4 kreg0[4], kreg1[4];
#pragma unroll
            for (int c = 0; c < 4; ++c) {
                int sw = ((hf * 4 + c) ^ (lane & 7)) * 8;
                kreg0[c] = *(const uint4*)&kf[r0 + sw];
                kreg1[c] = *(const uint4*)&kf[r0 + 64 + sw];
            }
#pragma unroll
            for (int c = 0; c < 4; ++c) {
                int cc = hf * 4 + c;
                uint k0p[4] = {kreg0[c].x, kreg0[c].y, kreg0[c].z, kreg0[c].w};
                uint k1p[4] = {kreg1[c].x, kreg1[c].y, kreg1[c].z, kreg1[c].w};
#pragma unroll
                for (int r = 0; r < 4; ++r) {
                    uint4 qu = *(const uint4*)&q_l[wv * 256 + r * 64 + cc * 8];
                    uint qp[4] = {qu.x, qu.y, qu.z, qu.w};
#if HAS_FDOT2
#pragma unroll
                    for (int p = 0; p < 4; ++p) {
                        f16x2_t qq = u2h(qp[p]);
                        acc0[r] = __builtin_amdgcn_fdot2(min2(qq, u2h(k0p[p])), one2, acc0[r], false);
                        acc1[r] = __builtin_amdgcn_fdot2(min2(qq, u2h(k1p[p])), one2, acc1[r], false);
                    }
#else
                    f16x2_t m0 = min2(u2h(qp[0]), u2h(k0p[0]));
                    f16x2_t m1 = min2(u2h(qp[0]), u2h(k1p[0]));
#pragma unroll
                    for (int p = 1; p < 4; ++p) {
                        m0 = m0 + min2(u2h(qp[p]), u2h(k0p[p]));
                        m1 = m1 + min2(u2h(qp[p]), u2h(k1p[p]));
                    }
                    acc0[r] += (float)m0[0] + (float)m0[1];
                    acc1[r] += (float)m1[0] + (float)m1[1];
#endif
                }
            }
        }
        float2 ks2 = *(const float2*)&ks_l[jb + 2 * lane];
#pragma unroll
        for (int r = 0; r < 4; ++r) {
            float s0 = qs_r[r] + ks2.x, s1 = qs_r[r] + ks2.y;
            float e0 = __expf((2.f * acc0[r]) / (s0 + 2e-8f));
            float e1 = __expf((2.f * acc1[r]) / (s1 + 2e-8f));
            float sum = e0 + e1;
#pragma unroll
            for (int m = 1; m < 64; m <<= 1) sum += __shfl_xor(sum, m, 64);
            den_r[r] += sum;
            uint pw = (uint)f_to_bf16bits(e0) | ((uint)f_to_bf16bits(e1) << 16);
            int i = wv * 4 + r;
            *(uint*)&p_l[(i * 256 + jb + 2 * lane) ^ ((i & 7) * 8)] = pw;
        }
    }
    if (lane == 0) {
#pragma unroll
        for (int r = 0; r < 4; ++r) den_l[wv * 4 + r] = den_r[r];
    }
    __syncthreads();

    const ushort* vb = vgt + (size_t)head * KGP + (size_t)(16 * wv + l15) * 256;
    f32x4_t accv = {0.f, 0.f, 0.f, 0.f};
#pragma unroll
    for (int st = 0; st < 8; ++st) {
        bf16x8_t a = *(const bf16x8_t*)&p_l[(l15 * 256 + st * 32 + quad * 8) ^ ((l15 & 7) * 8)];
        bf16x8_t b = *(const bf16x8_t*)&vb[st * 32 + quad * 8];
        accv = __builtin_amdgcn_mfma_f32_16x16x32_bf16(a, b, accv, 0, 0, 0);
    }
    float4 dv = *(const float4*)&den_l[quad * 4];
    float dar[4] = {dv.x, dv.y, dv.z, dv.w};
#pragma unroll
    for (int t = 0; t < 4; ++t) {
        int ig = ch * 16 + quad * 4 + t;
        if (ig < nrows)
            ao[((size_t)(bb * nrows + ig)) * E_ + hh * DH_ + 16 * wv + l15] =
                __float2bfloat16(accv[t] / dar[t]);
    }
}

// ---------------- head: fused fc2-splitK reduce + final LN + classifier ----------------
__global__ __launch_bounds__(256) void head_ln_kernel(const float* __restrict__ hc,
                                                      const float* __restrict__ pc0,
                                                      const float* __restrict__ pc1,
                                                      const float* __restrict__ fb,
                                                      const float* __restrict__ lw,
                                                      const float* __restrict__ lb,
                                                      const float* __restrict__ hw,
                                                      const float* __restrict__ hb,
                                                      float* __restrict__ out) {
    int b = blockIdx.y;
    int tid = threadIdx.x;
    const float* xr0 = hc  + (size_t)b * E_;
    const float* pr0 = pc0 + (size_t)b * E_;
    const float* pr1 = pc1 + (size_t)b * E_;
    float v0 = xr0[tid]       + pr0[tid]       + pr1[tid]       + fb[tid];
    float v1 = xr0[tid + 256] + pr0[tid + 256] + pr1[tid + 256] + fb[tid + 256];
    float v2 = xr0[tid + 512] + pr0[tid + 512] + pr1[tid + 512] + fb[tid + 512];
    float s  = v0 + v1 + v2;
    float sq = v0 * v0 + v1 * v1 + v2 * v2;
#pragma unroll
    for (int m = 1; m < 64; m <<= 1) {
        s  += __shfl_xor(s, m, 64);
        sq += __shfl_xor(sq, m, 64);
    }
    __shared__ float ss[4], sqs[4];
    __shared__ float xr[E_];
    __shared__ float partial[4][64];
    int wave = tid >> 6, lane = tid & 63;
    if (lane == 0) { ss[wave] = s; sqs[wave] = sq; }
    __syncthreads();
    s  = ss[0] + ss[1] + ss[2] + ss[3];
    sq = sqs[0] + sqs[1] + sqs[2] + sqs[3];
    float mu   = s * (1.0f / 768.0f);
    float var  = sq * (1.0f / 768.0f) - mu * mu;
    float rstd = rsqrtf(var + 1e-5f);
    xr[tid]       = (v0 - mu) * rstd * lw[tid]       + lb[tid];
    xr[tid + 256] = (v1 - mu) * rstd * lw[tid + 256] + lb[tid + 256];
    xr[tid + 512] = (v2 - mu) * rstd * lw[tid + 512] + lb[tid + 512];
    __syncthreads();
    int nl = tid & 63, eq = tid >> 6;
    int n = blockIdx.x * 64 + nl;
    float acc = 0.f;
    if (n < OUT_) {
        int e0 = eq * 192;
        for (int e = e0; e < e0 + 192; ++e) acc += xr[e] * hw[(size_t)e * OUT_ + n];
    }
    partial[eq][nl] = acc;
    __syncthreads();
    if (eq == 0 && n < OUT_)
        out[(size_t)b * OUT_ + n] = partial[0][nl] + partial[1][nl] + partial[2][nl] + partial[3][nl] + hb[n];
}

extern "C" void kernel_launch(void* const* d_in, const int* in_sizes, int n_in,
                              void* d_out, int out_size, void* d_ws, size_t ws_size,
                              hipStream_t stream) {
    const float* x        = (const float*)d_in[0];
    const float* conv_w   = (const float*)d_in[1];
    const float* conv_b   = (const float*)d_in[2];
    const float* pos_e    = (const float*)d_in[3];
    const float* cls_t    = (const float*)d_in[4];
    const float* ln1_w    = (const float*)d_in[5];
    const float* ln1_b    = (const float*)d_in[6];
    const float* attn_w   = (const float*)d_in[7];
    const float* attn_b   = (const float*)d_in[8];
    const float* proj_w   = (const float*)d_in[9];
    const float* proj_b   = (const float*)d_in[10];
    const float* ln2_w    = (const float*)d_in[11];
    const float* ln2_b    = (const float*)d_in[12];
    const float* fc1_w    = (const float*)d_in[13];
    const float* fc1_b    = (const float*)d_in[14];
    const float* fc2_w    = (const float*)d_in[15];
    const float* fc2_b    = (const float*)d_in[16];
    const float* lnf_w    = (const float*)d_in[17];
    const float* lnf_b    = (const float*)d_in[18];
    const float* head_w   = (const float*)d_in[19];
    const float* head_b   = (const float*)d_in[20];
    float* out = (float*)d_out;

    // workspace layout (unchanged offsets; part0q/part1q regions now unused)
    float* h       = (float*)d_ws;                 // 605184
    float* part0q  = h + 605184;                   // (unused)
    float* part1q  = part0q + 1815552;             // (unused)
    float* part    = part1q + 1815552;             // 2x605184 (patch/proj/fc2 parts)
    float* hc      = part + 3631104;               // 3072
    float* partc   = hc + 3072;                    // 6144
    float* ksg     = partc + 6144;                 // 12288
    float* qsg     = ksg + 12288;                  // 9600
    __hip_bfloat16* lnb  = (__hip_bfloat16*)(qsg + 9600);   // 605184
    __hip_bfloat16* ao   = lnb + 605184;                    // 605184
    __hip_bfloat16* hid  = ao + 605184;                     // 2420736
    __hip_bfloat16* aim  = hid + 2420736;                   // 602112
    __hip_bfloat16* wt   = aim + 602112;                    // 14745600
    ushort* kg  = (ushort*)(wt + 14745600);                 // 786432
    ushort* vgt = kg + 786432;                              // 786432
    ushort* qg  = vgt + 786432;                             // 605184
    __hip_bfloat16* lnb4 = (__hip_bfloat16*)(qg + 605184);  // 3072
    __hip_bfloat16* hid4 = lnb4 + 3072;                     // 12288

    // ---- prologue ----
    prep_all_kernel<<<5388, 256, 0, stream>>>(x, aim, attn_w, proj_w, fc1_w, fc2_w, conv_w, wt, vgt);
    {
        dim3 grid(E_ / 64, 13, 2);
        gemm_mfma_kernel<<<grid, 256, 0, stream>>>(aim, wt + WT_CONV, nullptr, nullptr, nullptr,
                                                   nullptr, part, 784, E_, E_, 0, 2, 0, E_, 0);
    }
    embed_ln_kernel<<<ROWS_, 256, 0, stream>>>(part, part + 602112, conv_b,
                                               pos_e, cls_t, ln1_w, ln1_b, h, lnb);

    // ---- layer 0 (full 788 rows) ----
    {
        const __hip_bfloat16* wl = wt + WT_LBASE;
        {
            dim3 grid(36, 13);     // Q,K,V cols 0..2304, KS=1, fused attn-prep epilogue
            gemm_qkv_kernel<<<grid, 256, 0, stream>>>(lnb, wl + WT_QKV, attn_b,
                                                      qg, qsg, kg, ksg, vgt, 0);
        }
        tversky_attn_kernel<<<dim3(13, NH_, B_), 256, 0, stream>>>(
            qg, kg, ksg, vgt, qsg, ao, S_);
        {
            dim3 grid(E_ / 64, 13, 2);
            gemm_mfma_kernel<<<grid, 256, 0, stream>>>(ao, wl + WT_PROJ, nullptr, nullptr, nullptr,
                                                       nullptr, part, ROWS_, E_, E_, 0, 2, 0, E_, 0);
        }
        reduce_ln_kernel<<<ROWS_, 256, 0, stream>>>(part, 2, 605184, proj_b,
                                                    h, ln2_w, ln2_b, lnb);
        {
            dim3 grid(DFF_ / 64, 13);
            gemm_mfma_kernel<<<grid, 256, 0, stream>>>(lnb, wl + WT_FC1, fc1_b,
                                                       nullptr, nullptr, hid, nullptr,
                                                       ROWS_, DFF_, E_, 1, 1, 0, DFF_, 0);
        }
        {
            dim3 grid(E_ / 64, 13, 2);
            gemm_mfma_kernel<<<grid, 256, 0, stream>>>(hid, wl + WT_FC2, nullptr, nullptr, nullptr,
                                                       nullptr, part, ROWS_, E_, DFF_, 0, 2, 0, E_, 0);
        }
        reduce_ln_kernel<<<ROWS_, 256, 0, stream>>>(part, 2, 605184, fc2_b,
                                                    h, ln1_w + E_, ln1_b + E_, lnb);
    }

    // ---- layer 1: only CLS rows (4) needed downstream; K,V via fused-epilogue GEMM ----
    {
        const __hip_bfloat16* wl = wt + WT_LBASE + WT_LSTRIDE;
        {
            dim3 grid(24, 13);     // cols 768..2304 (K,V only), KS=1
            gemm_qkv_kernel<<<grid, 256, 0, stream>>>(lnb, wl + WT_QKV, attn_b + 3 * E_,
                                                      qg, qsg, kg, ksg, vgt, 768);
        }
        cls_q_kernel<<<dim3(NH_, B_), 256, 0, stream>>>(
            lnb, attn_w + (size_t)E_ * 3 * E_, attn_b + 3 * E_, qg, qsg);
        tversky_attn_kernel<<<dim3(1, NH_, B_), 256, 0, stream>>>(
            qg, kg, ksg, vgt, qsg, ao, 1);
        {
            dim3 grid(E_ / 64, 1, 1);
            gemm_mfma_kernel<<<grid, 256, 0, stream>>>(ao, wl + WT_PROJ, proj_b + E_, h,
                                                       hc, nullptr, nullptr,
                                                       4, E_, E_, 0, 1, S_ * E_, E_, 0);
        }
        layernorm_kernel<<<4, 256, 0, stream>>>(hc, ln2_w + E_, ln2_b + E_, lnb4);
        {
            dim3 grid(DFF_ / 64, 1, 1);
            gemm_mfma_kernel<<<grid, 256, 0, stream>>>(lnb4, wl + WT_FC1, fc1_b + DFF_,
                                                       nullptr, nullptr, hid4, nullptr,
                                                       4, DFF_, E_, 1, 1, 0, DFF_, 0);
        }
        {
            dim3 grid(E_ / 64, 1, 2);
            gemm_mfma_kernel<<<grid, 256, 0, stream>>>(hid4, wl + WT_FC2, nullptr, nullptr, nullptr,
                                                       nullptr, partc, 4, E_, DFF_, 0, 2, 0, E_, 0);
        }
    }

    {
        dim3 grid((OUT_ + 63) / 64, B_);
        head_ln_kernel<<<grid, 256, 0, stream>>>(hc, partc, partc + 3072, fc2_b + E_,
                                                 lnf_w, lnf_b, head_w, head_b, out);
    }
}

// Round 8
// 303.958 us; speedup vs baseline: 1.2375x; 1.0458x over previous
//
#include <hip/hip_runtime.h>
#include <hip/hip_bf16.h>
#include <math.h>

// Shapes
#define B_  4
#define E_  768
#define NH_ 12
#define DH_ 64
#define DFF_ 3072
#define OUT_ 1000
#define S_  197
#define ROWS_ 788          // B_*S_
#define QH_P 12608         // 197*64 per-head q pitch
#define KGP  16384         // 256*64 per-head k / v^T pitch

typedef __bf16 bf16x8_t __attribute__((ext_vector_type(8)));
typedef float f32x4_t __attribute__((ext_vector_type(4)));
typedef _Float16 f16x2_t __attribute__((ext_vector_type(2)));

#define HAS_FDOT2 __has_builtin(__builtin_amdgcn_fdot2)

__device__ __forceinline__ float gelu_f(float x) {
    float x3 = x * x * x;
    return 0.5f * x * (1.0f + tanhf(0.7978845608028654f * (x + 0.044715f * x3)));
}
__device__ __forceinline__ ushort f_to_bf16bits(float f) {
    __hip_bfloat16 b = __float2bfloat16(f);
    return *(ushort*)&b;
}
__device__ __forceinline__ ushort f_to_f16bits(float f) {
    _Float16 h = (_Float16)f;
    return __builtin_bit_cast(ushort, h);
}
__device__ __forceinline__ f16x2_t u2h(uint u) { return __builtin_bit_cast(f16x2_t, u); }
__device__ __forceinline__ f16x2_t min2(f16x2_t a, f16x2_t b) {
    return __builtin_elementwise_min(a, b);
}

// ---------------- merged prologue prep: im2col + reg-transpose weights + conv cvt + vgt pad zero ----------------
#define WT_CONV   0
#define WT_LBASE  589824
#define WT_LSTRIDE 7077888
#define WT_QKV    0
#define WT_PROJ   1769472
#define WT_FC1    2359296
#define WT_FC2    4718592
__global__ __launch_bounds__(256) void prep_all_kernel(const float* __restrict__ x,
                                                       __hip_bfloat16* __restrict__ aim,
                                                       const float* __restrict__ attn_w,
                                                       const float* __restrict__ proj_w,
                                                       const float* __restrict__ fc1_w,
                                                       const float* __restrict__ fc2_w,
                                                       const float* __restrict__ conv_w,
                                                       __hip_bfloat16* __restrict__ wt,
                                                       ushort* __restrict__ vgt) {
    int bid = blockIdx.x;
    if (bid < 588) {                        // im2col, 4 elems/thread
        int id = bid * 256 + threadIdx.x;   // 0..150527
        int row = id / 192, k4 = (id - row * 192) * 4;
        int b = row / 196, pr = row - b * 196;
        int hp = pr / 14, wp = pr - hp * 14;
        int c = k4 >> 8, rem = k4 & 255, p = rem >> 4, q = rem & 15;
        float4 v = *(const float4*)&x[(((size_t)(b * 3 + c) * 224) + hp * 16 + p) * 224 + wp * 16 + q];
        ushort4 o = make_ushort4(f_to_bf16bits(v.x), f_to_bf16bits(v.y), f_to_bf16bits(v.z), f_to_bf16bits(v.w));
        *(ushort4*)((ushort*)aim + (size_t)row * 768 + k4) = o;
        return;
    }
    int id = bid - 588;
    if (id < 3456) {                        // 64x64 register transpose tiles
        int l = id / 1728, r = id - l * 1728;
        const float* src;
        __hip_bfloat16* dst;
        int K, N, tile;
        size_t lbase = WT_LBASE + (size_t)l * WT_LSTRIDE;
        if (r < 432)       { src = attn_w + (size_t)l * E_ * 3 * E_; dst = wt + lbase + WT_QKV;  K = E_;   N = 3 * E_; tile = r; }
        else if (r < 576)  { src = proj_w + (size_t)l * E_ * E_;     dst = wt + lbase + WT_PROJ; K = E_;   N = E_;     tile = r - 432; }
        else if (r < 1152) { src = fc1_w + (size_t)l * E_ * DFF_;    dst = wt + lbase + WT_FC1;  K = E_;   N = DFF_;   tile = r - 576; }
        else               { src = fc2_w + (size_t)l * DFF_ * E_;    dst = wt + lbase + WT_FC2;  K = DFF_; N = E_;     tile = r - 1152; }
        int ntn = N >> 6;
        int kb = (tile / ntn) * 64, nb = (tile % ntn) * 64;
        int kq = (threadIdx.x & 15) * 4, nq = (threadIdx.x >> 4) * 4;
        const float* s0 = src + (size_t)(kb + kq) * N + nb + nq;
        float4 v0 = *(const float4*)(s0);
        float4 v1 = *(const float4*)(s0 + N);
        float4 v2 = *(const float4*)(s0 + 2 * N);
        float4 v3 = *(const float4*)(s0 + 3 * N);
        __hip_bfloat16* d0 = dst + (size_t)(nb + nq) * K + kb + kq;
        *(ushort4*)(d0)         = make_ushort4(f_to_bf16bits(v0.x), f_to_bf16bits(v1.x), f_to_bf16bits(v2.x), f_to_bf16bits(v3.x));
        *(ushort4*)(d0 + K)     = make_ushort4(f_to_bf16bits(v0.y), f_to_bf16bits(v1.y), f_to_bf16bits(v2.y), f_to_bf16bits(v3.y));
        *(ushort4*)(d0 + 2 * K) = make_ushort4(f_to_bf16bits(v0.z), f_to_bf16bits(v1.z), f_to_bf16bits(v2.z), f_to_bf16bits(v3.z));
        *(ushort4*)(d0 + 3 * K) = make_ushort4(f_to_bf16bits(v0.w), f_to_bf16bits(v1.w), f_to_bf16bits(v2.w), f_to_bf16bits(v3.w));
        return;
    }
    id -= 3456;
    if (id < 576) {                          // conv cvt (already [N,K]), 4/thread
        int off = (id * 256 + threadIdx.x) * 4;
        float4 v = *(const float4*)&conv_w[off];
        ushort4 o = make_ushort4(f_to_bf16bits(v.x), f_to_bf16bits(v.y), f_to_bf16bits(v.z), f_to_bf16bits(v.w));
        *(ushort4*)((ushort*)wt + WT_CONV + off) = o;
        return;
    }
    id -= 576;
    {                                        // zero vgt (48*16384 ushorts) so pad j-cols stay 0 forever
        int off = (id * 256 + threadIdx.x) * 4;
        *(ushort4*)&vgt[off] = make_ushort4(0, 0, 0, 0);
    }
}

// ---------------- MFMA GEMM 64x64: LDS dbuf, prefetch depth 2, split-K, partial n-offset ----------------
#define BK 64
#define AP 72
__global__ __launch_bounds__(256) void gemm_mfma_kernel(const __hip_bfloat16* __restrict__ A,
                                                        const __hip_bfloat16* __restrict__ WT,
                                                        const float* __restrict__ bias,
                                                        const float* __restrict__ res,
                                                        float* __restrict__ Cf,
                                                        __hip_bfloat16* __restrict__ Cb,
                                                        float* __restrict__ partbase,
                                                        int M, int N, int K, int act, int KS,
                                                        int res_pitch, int pn, int nofs) {
    __shared__ __align__(16) ushort Asb[2][64 * AP];
    __shared__ __align__(16) ushort Bsb[2][64 * AP];
    const int tid = threadIdx.x;
    const int wave = tid >> 6, lane = tid & 63;
    const int quad = lane >> 4, l15 = lane & 15;
    const int wm = wave >> 1, wn = wave & 1;
    const int m0 = blockIdx.y * 64, n0 = blockIdx.x * 64;

    const int Kc   = K / KS;
    const int kbeg = blockIdx.z * Kc;
    const int n_it = Kc / BK;

    f32x4_t acc[2][2] = {};

    const int c0r = tid >> 3,         c0o = (tid & 7) * 8;
    const int c1r = (tid + 256) >> 3, c1o = c0o;

    uint4 pa0, pa1, pb0, pb1;
    auto load_tile = [&](int kk) {
        pa0 = make_uint4(0, 0, 0, 0);
        pa1 = pa0;
        int gm = m0 + c0r;
        if (gm < M) pa0 = *(const uint4*)&A[(size_t)gm * K + kk + c0o];
        gm = m0 + c1r;
        if (gm < M) pa1 = *(const uint4*)&A[(size_t)gm * K + kk + c1o];
        pb0 = *(const uint4*)&WT[(size_t)(n0 + c0r) * K + kk + c0o];
        pb1 = *(const uint4*)&WT[(size_t)(n0 + c1r) * K + kk + c1o];
    };
    auto store_tile = [&](int buf) {
        *(uint4*)&Asb[buf][c0r * AP + c0o] = pa0;
        *(uint4*)&Asb[buf][c1r * AP + c1o] = pa1;
        *(uint4*)&Bsb[buf][c0r * AP + c0o] = pb0;
        *(uint4*)&Bsb[buf][c1r * AP + c1o] = pb1;
    };

    load_tile(kbeg);
    store_tile(0);
    if (n_it > 1) load_tile(kbeg + BK);
    __syncthreads();

    for (int it = 0; it < n_it; ++it) {
        const int cur = it & 1, nxt = cur ^ 1;
        if (it + 1 < n_it) {
            store_tile(nxt);
            if (it + 2 < n_it) load_tile(kbeg + (it + 2) * BK);
        }
        const ushort* As = Asb[cur];
        const ushort* Bs = Bsb[cur];
#pragma unroll
        for (int ks = 0; ks < BK; ks += 32) {
            bf16x8_t a0 = *(const bf16x8_t*)&As[(32 * wm + l15) * AP + ks + 8 * quad];
            bf16x8_t a1 = *(const bf16x8_t*)&As[(32 * wm + 16 + l15) * AP + ks + 8 * quad];
            bf16x8_t b0 = *(const bf16x8_t*)&Bs[(32 * wn + l15) * AP + ks + 8 * quad];
            bf16x8_t b1 = *(const bf16x8_t*)&Bs[(32 * wn + 16 + l15) * AP + ks + 8 * quad];
            acc[0][0] = __builtin_amdgcn_mfma_f32_16x16x32_bf16(a0, b0, acc[0][0], 0, 0, 0);
            acc[0][1] = __builtin_amdgcn_mfma_f32_16x16x32_bf16(a0, b1, acc[0][1], 0, 0, 0);
            acc[1][0] = __builtin_amdgcn_mfma_f32_16x16x32_bf16(a1, b0, acc[1][0], 0, 0, 0);
            acc[1][1] = __builtin_amdgcn_mfma_f32_16x16x32_bf16(a1, b1, acc[1][1], 0, 0, 0);
        }
        __syncthreads();
    }

    if (partbase) {
        float* P = partbase + (size_t)blockIdx.z * M * pn;
#pragma unroll
        for (int mi = 0; mi < 2; ++mi)
#pragma unroll
            for (int ni = 0; ni < 2; ++ni) {
                int gn = n0 + 32 * wn + 16 * ni + l15;
#pragma unroll
                for (int r = 0; r < 4; ++r) {
                    int gm = m0 + 32 * wm + 16 * mi + quad * 4 + r;
                    if (gm < M) P[(size_t)gm * pn + nofs + gn] = acc[mi][ni][r];
                }
            }
        return;
    }

#pragma unroll
    for (int mi = 0; mi < 2; ++mi)
#pragma unroll
        for (int ni = 0; ni < 2; ++ni) {
            int gn = n0 + 32 * wn + 16 * ni + l15;
#pragma unroll
            for (int r = 0; r < 4; ++r) {
                int gm = m0 + 32 * wm + 16 * mi + quad * 4 + r;
                if (gm < M) {
                    float v = acc[mi][ni][r] + bias[gn];
                    if (act == 1) v = gelu_f(v);
                    if (res) v += res[(size_t)gm * res_pitch + gn];
                    if (Cf) Cf[(size_t)gm * N + gn] = v;
                    else    Cb[(size_t)gm * N + gn] = __float2bfloat16(v);
                }
            }
        }
}

// ---------------- QKV GEMM with fused attention-prep epilogue (+ packed CLS-Q matvec path) ----------------
// blockIdx.x < nqkv: GEMM tile (each 64-col tile is one head's d-range; region/head block-uniform)
//   region 0 (Q): relu -> qg f16 + qs row-sums; region 1 (K): relu -> kg f16 + ks row-sums
//   region 2 (V): -> vgt bf16 [head][d*256+j] (transposed scatter; pad j stays 0 from prep)
// blockIdx.x >= nqkv (layer 1 only): CLS-row Q matvec from fp32 weights (bb = x-nqkv, hh = y; y<12)
__global__ __launch_bounds__(256) void gemm_qkv_kernel(const __hip_bfloat16* __restrict__ A,
                                                       const __hip_bfloat16* __restrict__ WT,
                                                       const float* __restrict__ ab,
                                                       ushort* __restrict__ qg,
                                                       float* __restrict__ qsg,
                                                       ushort* __restrict__ kg,
                                                       float* __restrict__ ksg,
                                                       ushort* __restrict__ vgt,
                                                       int ncol0, int nqkv,
                                                       const float* __restrict__ wraw) {
    const int tid = threadIdx.x;
    const int wave = tid >> 6, lane = tid & 63;

    if ((int)blockIdx.x >= nqkv) {           // ---- CLS-Q matvec path (layer 1) ----
        if (blockIdx.y >= NH_) return;
        const int hh = blockIdx.y, bb = blockIdx.x - nqkv;
        const int head = bb * NH_ + hh;
        __shared__ float sacc[4][64];
        const __hip_bfloat16* xr = A + (size_t)(bb * S_) * E_;
        const float* wcol = wraw + hh * DH_;
        float acc = 0.f;
        const int k0 = wave * 192;
#pragma unroll 4
        for (int k = k0; k < k0 + 192; ++k)
            acc += __bfloat162float(xr[k]) * wcol[(size_t)k * (3 * E_) + lane];
        sacc[wave][lane] = acc;
        __syncthreads();
        if (tid < 64) {
            float q = sacc[0][tid] + sacc[1][tid] + sacc[2][tid] + sacc[3][tid] + ab[hh * DH_ + tid];
            q = fmaxf(q, 0.f);
            qg[(size_t)head * QH_P + tid] = f_to_f16bits(q);
            float s = q;
#pragma unroll
            for (int m = 1; m < 64; m <<= 1) s += __shfl_xor(s, m, 64);
            if (tid == 0) qsg[(size_t)head * 200] = s;
        }
        return;
    }

    __shared__ __align__(16) ushort Asb[2][64 * AP];
    __shared__ __align__(16) ushort Bsb[2][64 * AP];
    __shared__ float rs[2][64];
    const int quad = lane >> 4, l15 = lane & 15;
    const int wm = wave >> 1, wn = wave & 1;
    const int m0 = blockIdx.y * 64;
    const int n0g = ncol0 + blockIdx.x * 64;

    f32x4_t acc[2][2] = {};

    const int c0r = tid >> 3,         c0o = (tid & 7) * 8;
    const int c1r = (tid + 256) >> 3, c1o = c0o;

    uint4 pa0, pa1, pb0, pb1;
    auto load_tile = [&](int kk) {
        pa0 = make_uint4(0, 0, 0, 0);
        pa1 = pa0;
        int gm = m0 + c0r;
        if (gm < ROWS_) pa0 = *(const uint4*)&A[(size_t)gm * E_ + kk + c0o];
        gm = m0 + c1r;
        if (gm < ROWS_) pa1 = *(const uint4*)&A[(size_t)gm * E_ + kk + c1o];
        pb0 = *(const uint4*)&WT[(size_t)(n0g + c0r) * E_ + kk + c0o];
        pb1 = *(const uint4*)&WT[(size_t)(n0g + c1r) * E_ + kk + c1o];
    };
    auto store_tile = [&](int buf) {
        *(uint4*)&Asb[buf][c0r * AP + c0o] = pa0;
        *(uint4*)&Asb[buf][c1r * AP + c1o] = pa1;
        *(uint4*)&Bsb[buf][c0r * AP + c0o] = pb0;
        *(uint4*)&Bsb[buf][c1r * AP + c1o] = pb1;
    };

    load_tile(0);
    store_tile(0);
    load_tile(BK);
    __syncthreads();

    const int n_it = E_ / BK;   // 12
    for (int it = 0; it < n_it; ++it) {
        const int cur = it & 1, nxt = cur ^ 1;
        if (it + 1 < n_it) {
            store_tile(nxt);
            if (it + 2 < n_it) load_tile((it + 2) * BK);
        }
        const ushort* As = Asb[cur];
        const ushort* Bs = Bsb[cur];
#pragma unroll
        for (int ks = 0; ks < BK; ks += 32) {
            bf16x8_t a0 = *(const bf16x8_t*)&As[(32 * wm + l15) * AP + ks + 8 * quad];
            bf16x8_t a1 = *(const bf16x8_t*)&As[(32 * wm + 16 + l15) * AP + ks + 8 * quad];
            bf16x8_t b0 = *(const bf16x8_t*)&Bs[(32 * wn + l15) * AP + ks + 8 * quad];
            bf16x8_t b1 = *(const bf16x8_t*)&Bs[(32 * wn + 16 + l15) * AP + ks + 8 * quad];
            acc[0][0] = __builtin_amdgcn_mfma_f32_16x16x32_bf16(a0, b0, acc[0][0], 0, 0, 0);
            acc[0][1] = __builtin_amdgcn_mfma_f32_16x16x32_bf16(a0, b1, acc[0][1], 0, 0, 0);
            acc[1][0] = __builtin_amdgcn_mfma_f32_16x16x32_bf16(a1, b0, acc[1][0], 0, 0, 0);
            acc[1][1] = __builtin_amdgcn_mfma_f32_16x16x32_bf16(a1, b1, acc[1][1], 0, 0, 0);
        }
        __syncthreads();
    }

    const int region = n0g / 768;            // 0=Q, 1=K, 2=V (block-uniform)
    const int hh = (n0g >> 6) % 12;          // head within region (block-uniform)
    const float bias0 = ab[n0g + 32 * wn + l15];
    const float bias1 = ab[n0g + 32 * wn + 16 + l15];

    float rsum[2][4] = {};
#pragma unroll
    for (int mi = 0; mi < 2; ++mi)
#pragma unroll
        for (int ni = 0; ni < 2; ++ni) {
            const int d = 32 * wn + 16 * ni + l15;
#pragma unroll
            for (int r = 0; r < 4; ++r) {
                int gm = m0 + 32 * wm + 16 * mi + quad * 4 + r;
                if (gm < ROWS_) {
                    float v = acc[mi][ni][r] + (ni ? bias1 : bias0);
                    int b = gm / S_, j = gm - b * S_;
                    int head = b * NH_ + hh;
                    if (region == 0) {
                        v = fmaxf(v, 0.f);
                        qg[(size_t)head * QH_P + j * 64 + d] = f_to_f16bits(v);
                        rsum[mi][r] += v;
                    } else if (region == 1) {
                        v = fmaxf(v, 0.f);
                        kg[(size_t)head * KGP + j * 64 + d] = f_to_f16bits(v);
                        rsum[mi][r] += v;
                    } else {
                        vgt[(size_t)head * KGP + d * 256 + j] = f_to_bf16bits(v);
                    }
                }
            }
        }

    if (region < 2) {     // row-sums: 2 ni (done) x 16 l15 (shfl) x 2 wn (LDS)
#pragma unroll
        for (int mi = 0; mi < 2; ++mi)
#pragma unroll
            for (int r = 0; r < 4; ++r) {
                float s = rsum[mi][r];
                s += __shfl_xor(s, 1, 64);
                s += __shfl_xor(s, 2, 64);
                s += __shfl_xor(s, 4, 64);
                s += __shfl_xor(s, 8, 64);
                rsum[mi][r] = s;
            }
        if (l15 == 0) {
#pragma unroll
            for (int mi = 0; mi < 2; ++mi)
#pragma unroll
                for (int r = 0; r < 4; ++r)
                    rs[wn][32 * wm + 16 * mi + quad * 4 + r] = rsum[mi][r];
        }
        __syncthreads();
        if (tid < 64) {
            int gm = m0 + tid;
            if (gm < ROWS_) {
                int b = gm / S_, j = gm - b * S_;
                int head = b * NH_ + hh;
                float s = rs[0][tid] + rs[1][tid];
                if (region == 0) qsg[(size_t)head * 200 + j] = s;
                else             ksg[(size_t)head * 256 + j] = s;
            }
        }
    }
}

// ---------------- embed (split-K patch parts + conv_b + pe) + cls + LN1(l=0) fused ----------------
__global__ __launch_bounds__(256) void embed_ln_kernel(const float* __restrict__ p0,
                                                       const float* __restrict__ p1,
                                                       const float* __restrict__ cb,
                                                       const float* __restrict__ pe,
                                                       const float* __restrict__ ct,
                                                       const float* __restrict__ lw,
                                                       const float* __restrict__ lb,
                                                       float* __restrict__ h,
                                                       __hip_bfloat16* __restrict__ y) {
    int row = blockIdx.x, tid = threadIdx.x;
    int b = row / S_, s = row - b * S_;
    float v[3];
#pragma unroll
    for (int c = 0; c < 3; ++c) {
        int e = tid + c * 256;
        float t;
        if (s == 0) t = ct[e];
        else {
            int pr = s - 1;
            size_t gi = (size_t)(b * 196 + pr) * E_ + e;
            t = p0[gi] + p1[gi] + cb[e] + pe[(size_t)pr * E_ + e];
        }
        h[(size_t)row * E_ + e] = t;
        v[c] = t;
    }
    float sm = v[0] + v[1] + v[2];
    float sq = v[0] * v[0] + v[1] * v[1] + v[2] * v[2];
#pragma unroll
    for (int m = 1; m < 64; m <<= 1) {
        sm += __shfl_xor(sm, m, 64);
        sq += __shfl_xor(sq, m, 64);
    }
    __shared__ float ss[4], sqs[4];
    int wave = tid >> 6, lane = tid & 63;
    if (lane == 0) { ss[wave] = sm; sqs[wave] = sq; }
    __syncthreads();
    sm = ss[0] + ss[1] + ss[2] + ss[3];
    sq = sqs[0] + sqs[1] + sqs[2] + sqs[3];
    float mu   = sm * (1.0f / 768.0f);
    float var  = sq * (1.0f / 768.0f) - mu * mu;
    float rstd = rsqrtf(var + 1e-5f);
    __hip_bfloat16* yr = y + (size_t)row * E_;
#pragma unroll
    for (int c = 0; c < 3; ++c) {
        int e = tid + c * 256;
        yr[e] = __float2bfloat16((v[c] - mu) * rstd * lw[e] + lb[e]);
    }
}

// ---------------- LayerNorm (fp32 in, bf16 out) ----------------
__global__ __launch_bounds__(256) void layernorm_kernel(const float* __restrict__ x,
                                                        const float* __restrict__ w,
                                                        const float* __restrict__ b,
                                                        __hip_bfloat16* __restrict__ y) {
    int row = blockIdx.x;
    const float* xr = x + (size_t)row * E_;
    int tid = threadIdx.x;
    float v0 = xr[tid], v1 = xr[tid + 256], v2 = xr[tid + 512];
    float s  = v0 + v1 + v2;
    float sq = v0 * v0 + v1 * v1 + v2 * v2;
#pragma unroll
    for (int m = 1; m < 64; m <<= 1) {
        s  += __shfl_xor(s, m, 64);
        sq += __shfl_xor(sq, m, 64);
    }
    __shared__ float ss[4], sqs[4];
    int wave = tid >> 6, lane = tid & 63;
    if (lane == 0) { ss[wave] = s; sqs[wave] = sq; }
    __syncthreads();
    s  = ss[0] + ss[1] + ss[2] + ss[3];
    sq = sqs[0] + sqs[1] + sqs[2] + sqs[3];
    float mu   = s * (1.0f / 768.0f);
    float var  = sq * (1.0f / 768.0f) - mu * mu;
    float rstd = rsqrtf(var + 1e-5f);
    __hip_bfloat16* yr = y + (size_t)row * E_;
    yr[tid]       = __float2bfloat16((v0 - mu) * rstd * w[tid]       + b[tid]);
    yr[tid + 256] = __float2bfloat16((v1 - mu) * rstd * w[tid + 256] + b[tid + 256]);
    yr[tid + 512] = __float2bfloat16((v2 - mu) * rstd * w[tid + 512] + b[tid + 512]);
}

// ---------------- fused split-K(np) reduce + bias + residual + LayerNorm ----------------
__global__ __launch_bounds__(256) void reduce_ln_kernel(const float* __restrict__ parts,
                                                        int np, size_t pstride,
                                                        const float* __restrict__ bias,
                                                        float* __restrict__ h,
                                                        const float* __restrict__ lw,
                                                        const float* __restrict__ lb,
                                                        __hip_bfloat16* __restrict__ y) {
    int row = blockIdx.x, tid = threadIdx.x;
    float v[3];
#pragma unroll
    for (int c = 0; c < 3; ++c) {
        int e = tid + c * 256;
        size_t gi = (size_t)row * E_ + e;
        float t = bias[e] + h[gi];
        for (int z = 0; z < np; ++z) t += parts[z * pstride + gi];
        h[gi] = t;
        v[c] = t;
    }
    float s  = v[0] + v[1] + v[2];
    float sq = v[0] * v[0] + v[1] * v[1] + v[2] * v[2];
#pragma unroll
    for (int m = 1; m < 64; m <<= 1) {
        s  += __shfl_xor(s, m, 64);
        sq += __shfl_xor(sq, m, 64);
    }
    __shared__ float ss[4], sqs[4];
    int wave = tid >> 6, lane = tid & 63;
    if (lane == 0) { ss[wave] = s; sqs[wave] = sq; }
    __syncthreads();
    s  = ss[0] + ss[1] + ss[2] + ss[3];
    sq = sqs[0] + sqs[1] + sqs[2] + sqs[3];
    float mu   = s * (1.0f / 768.0f);
    float var  = sq * (1.0f / 768.0f) - mu * mu;
    float rstd = rsqrtf(var + 1e-5f);
    __hip_bfloat16* yr = y + (size_t)row * E_;
#pragma unroll
    for (int c = 0; c < 3; ++c) {
        int e = tid + c * 256;
        yr[e] = __float2bfloat16((v[c] - mu) * rstd * lw[e] + lb[e]);
    }
}

// ---------------- Tversky attention: score = 2*sum(min(q,k)) / (qs+ks+2eps) ----------------
// Pad rows j>=197 synthesized at LDS-stage time (k=-64 f16 = 0xD400, ks=0); kg/ksg hold
// only real rows. K consumed in two 4-chunk halves (round-6 non-spilling structure).
__global__ __launch_bounds__(256) void tversky_attn_kernel(const ushort* __restrict__ qg,
                                                           const ushort* __restrict__ kg,
                                                           const float* __restrict__ ksg,
                                                           const ushort* __restrict__ vgt,
                                                           const float* __restrict__ qsg,
                                                           __hip_bfloat16* __restrict__ ao,
                                                           int nrows) {
    __shared__ __align__(16) ushort kf[16384];   // 256 rows x 64 f16, chunk-swizzled
    __shared__ __align__(16) float ks_l[256];
    __shared__ __align__(16) ushort q_l[1024];   // [wave][4 rows][64] f16
    __shared__ __align__(16) ushort p_l[4096];   // [16 rows][256 j] bf16, swizzled
    __shared__ __align__(16) float den_l[16];

    const int tid = threadIdx.x, wv = tid >> 6, lane = tid & 63;
    const int quad = lane >> 4, l15 = lane & 15;
    const int ch = blockIdx.x, hh = blockIdx.y, bb = blockIdx.z;
    const int head = bb * NH_ + hh;

    {
        const ushort* kgh = kg + (size_t)head * KGP;
#pragma unroll
        for (int g = 0; g < 8; ++g) {
            int idx = g * 256 + tid;
            int row = idx >> 3, c = idx & 7;
            int sw = c ^ ((row >> 1) & 7);
            uint4 kv;
            if (row < S_) kv = *(const uint4*)&kgh[idx * 8];
            else kv = make_uint4(0xD400D400u, 0xD400D400u, 0xD400D400u, 0xD400D400u);
            *(uint4*)&kf[row * 64 + sw * 8] = kv;
        }
        ks_l[tid] = (tid < S_) ? ksg[(size_t)head * 256 + tid] : 0.f;
    }
    const int i0 = ch * 16 + wv * 4;
    if (lane < 32) {
        int r = lane >> 3, c = lane & 7;
        int i = i0 + r;
        uint4 qv = make_uint4(0, 0, 0, 0);
        if (i < nrows) qv = *(const uint4*)&qg[(size_t)head * QH_P + i * 64 + c * 8];
        *(uint4*)&q_l[wv * 256 + r * 64 + c * 8] = qv;
    }
    float qs_r[4];
#pragma unroll
    for (int r = 0; r < 4; ++r)
        qs_r[r] = (i0 + r < nrows) ? qsg[(size_t)head * 200 + i0 + r] : 0.f;
    __syncthreads();

#if HAS_FDOT2
    const f16x2_t one2 = __builtin_bit_cast(f16x2_t, 0x3C003C00u);
#endif
    float den_r[4] = {0.f, 0.f, 0.f, 0.f};
#pragma unroll
    for (int ph = 0; ph < 2; ++ph) {
        const int jb = ph * 128;
        const int r0 = (jb + 2 * lane) * 64;
        float acc0[4] = {0.f, 0.f, 0.f, 0.f};
        float acc1[4] = {0.f, 0.f, 0.f, 0.f};
#pragma unroll 1
        for (int hf = 0; hf < 2; ++hf) {
            uint4 kreg0[4], kreg1[4];
#pragma unroll
            for (int c = 0; c < 4; ++c) {
                int sw = ((hf * 4 + c) ^ (lane & 7)) * 8;
                kreg0[c] = *(const uint4*)&kf[r0 + sw];
                kreg1[c] = *(const uint4*)&kf[r0 + 64 + sw];
            }
#pragma unroll
            for (int c = 0; c < 4; ++c) {
                int cc = hf * 4 + c;
                uint k0p[4] = {kreg0[c].x, kreg0[c].y, kreg0[c].z, kreg0[c].w};
                uint k1p[4] = {kreg1[c].x, kreg1[c].y, kreg1[c].z, kreg1[c].w};
#pragma unroll
                for (int r = 0; r < 4; ++r) {
                    uint4 qu = *(const uint4*)&q_l[wv * 256 + r * 64 + cc * 8];
                    uint qp[4] = {qu.x, qu.y, qu.z, qu.w};
#if HAS_FDOT2
#pragma unroll
                    for (int p = 0; p < 4; ++p) {
                        f16x2_t qq = u2h(qp[p]);
                        acc0[r] = __builtin_amdgcn_fdot2(min2(qq, u2h(k0p[p])), one2, acc0[r], false);
                        acc1[r] = __builtin_amdgcn_fdot2(min2(qq, u2h(k1p[p])), one2, acc1[r], false);
                    }
#else
                    f16x2_t m0 = min2(u2h(qp[0]), u2h(k0p[0]));
                    f16x2_t m1 = min2(u2h(qp[0]), u2h(k1p[0]));
#pragma unroll
                    for (int p = 1; p < 4; ++p) {
                        m0 = m0 + min2(u2h(qp[p]), u2h(k0p[p]));
                        m1 = m1 + min2(u2h(qp[p]), u2h(k1p[p]));
                    }
                    acc0[r] += (float)m0[0] + (float)m0[1];
                    acc1[r] += (float)m1[0] + (float)m1[1];
#endif
                }
            }
        }
        float2 ks2 = *(const float2*)&ks_l[jb + 2 * lane];
#pragma unroll
        for (int r = 0; r < 4; ++r) {
            float s0 = qs_r[r] + ks2.x, s1 = qs_r[r] + ks2.y;
            float e0 = __expf((2.f * acc0[r]) / (s0 + 2e-8f));
            float e1 = __expf((2.f * acc1[r]) / (s1 + 2e-8f));
            float sum = e0 + e1;
#pragma unroll
            for (int m = 1; m < 64; m <<= 1) sum += __shfl_xor(sum, m, 64);
            den_r[r] += sum;
            uint pw = (uint)f_to_bf16bits(e0) | ((uint)f_to_bf16bits(e1) << 16);
            int i = wv * 4 + r;
            *(uint*)&p_l[(i * 256 + jb + 2 * lane) ^ ((i & 7) * 8)] = pw;
        }
    }
    if (lane == 0) {
#pragma unroll
        for (int r = 0; r < 4; ++r) den_l[wv * 4 + r] = den_r[r];
    }
    __syncthreads();

    const ushort* vb = vgt + (size_t)head * KGP + (size_t)(16 * wv + l15) * 256;
    f32x4_t accv = {0.f, 0.f, 0.f, 0.f};
#pragma unroll
    for (int st = 0; st < 8; ++st) {
        bf16x8_t a = *(const bf16x8_t*)&p_l[(l15 * 256 + st * 32 + quad * 8) ^ ((l15 & 7) * 8)];
        bf16x8_t b = *(const bf16x8_t*)&vb[st * 32 + quad * 8];
        accv = __builtin_amdgcn_mfma_f32_16x16x32_bf16(a, b, accv, 0, 0, 0);
    }
    float4 dv = *(const float4*)&den_l[quad * 4];
    float dar[4] = {dv.x, dv.y, dv.z, dv.w};
#pragma unroll
    for (int t = 0; t < 4; ++t) {
        int ig = ch * 16 + quad * 4 + t;
        if (ig < nrows)
            ao[((size_t)(bb * nrows + ig)) * E_ + hh * DH_ + 16 * wv + l15] =
                __float2bfloat16(accv[t] / dar[t]);
    }
}

// ---------------- head: fused fc2-splitK reduce + final LN + classifier ----------------
__global__ __launch_bounds__(256) void head_ln_kernel(const float* __restrict__ hc,
                                                      const float* __restrict__ pc0,
                                                      const float* __restrict__ pc1,
                                                      const float* __restrict__ fb,
                                                      const float* __restrict__ lw,
                                                      const float* __restrict__ lb,
                                                      const float* __restrict__ hw,
                                                      const float* __restrict__ hb,
                                                      float* __restrict__ out) {
    int b = blockIdx.y;
    int tid = threadIdx.x;
    const float* xr0 = hc  + (size_t)b * E_;
    const float* pr0 = pc0 + (size_t)b * E_;
    const float* pr1 = pc1 + (size_t)b * E_;
    float v0 = xr0[tid]       + pr0[tid]       + pr1[tid]       + fb[tid];
    float v1 = xr0[tid + 256] + pr0[tid + 256] + pr1[tid + 256] + fb[tid + 256];
    float v2 = xr0[tid + 512] + pr0[tid + 512] + pr1[tid + 512] + fb[tid + 512];
    float s  = v0 + v1 + v2;
    float sq = v0 * v0 + v1 * v1 + v2 * v2;
#pragma unroll
    for (int m = 1; m < 64; m <<= 1) {
        s  += __shfl_xor(s, m, 64);
        sq += __shfl_xor(sq, m, 64);
    }
    __shared__ float ss[4], sqs[4];
    __shared__ float xr[E_];
    __shared__ float partial[4][64];
    int wave = tid >> 6, lane = tid & 63;
    if (lane == 0) { ss[wave] = s; sqs[wave] = sq; }
    __syncthreads();
    s  = ss[0] + ss[1] + ss[2] + ss[3];
    sq = sqs[0] + sqs[1] + sqs[2] + sqs[3];
    float mu   = s * (1.0f / 768.0f);
    float var  = sq * (1.0f / 768.0f) - mu * mu;
    float rstd = rsqrtf(var + 1e-5f);
    xr[tid]       = (v0 - mu) * rstd * lw[tid]       + lb[tid];
    xr[tid + 256] = (v1 - mu) * rstd * lw[tid + 256] + lb[tid + 256];
    xr[tid + 512] = (v2 - mu) * rstd * lw[tid + 512] + lb[tid + 512];
    __syncthreads();
    int nl = tid & 63, eq = tid >> 6;
    int n = blockIdx.x * 64 + nl;
    float acc = 0.f;
    if (n < OUT_) {
        int e0 = eq * 192;
        for (int e = e0; e < e0 + 192; ++e) acc += xr[e] * hw[(size_t)e * OUT_ + n];
    }
    partial[eq][nl] = acc;
    __syncthreads();
    if (eq == 0 && n < OUT_)
        out[(size_t)b * OUT_ + n] = partial[0][nl] + partial[1][nl] + partial[2][nl] + partial[3][nl] + hb[n];
}

extern "C" void kernel_launch(void* const* d_in, const int* in_sizes, int n_in,
                              void* d_out, int out_size, void* d_ws, size_t ws_size,
                              hipStream_t stream) {
    const float* x        = (const float*)d_in[0];
    const float* conv_w   = (const float*)d_in[1];
    const float* conv_b   = (const float*)d_in[2];
    const float* pos_e    = (const float*)d_in[3];
    const float* cls_t    = (const float*)d_in[4];
    const float* ln1_w    = (const float*)d_in[5];
    const float* ln1_b    = (const float*)d_in[6];
    const float* attn_w   = (const float*)d_in[7];
    const float* attn_b   = (const float*)d_in[8];
    const float* proj_w   = (const float*)d_in[9];
    const float* proj_b   = (const float*)d_in[10];
    const float* ln2_w    = (const float*)d_in[11];
    const float* ln2_b    = (const float*)d_in[12];
    const float* fc1_w    = (const float*)d_in[13];
    const float* fc1_b    = (const float*)d_in[14];
    const float* fc2_w    = (const float*)d_in[15];
    const float* fc2_b    = (const float*)d_in[16];
    const float* lnf_w    = (const float*)d_in[17];
    const float* lnf_b    = (const float*)d_in[18];
    const float* head_w   = (const float*)d_in[19];
    const float* head_b   = (const float*)d_in[20];
    float* out = (float*)d_out;

    // workspace layout (unchanged offsets; part0q/part1q regions now unused)
    float* h       = (float*)d_ws;                 // 605184
    float* part0q  = h + 605184;                   // (unused)
    float* part1q  = part0q + 1815552;             // (unused)
    float* part    = part1q + 1815552;             // 2x605184 (patch/proj/fc2 parts)
    float* hc      = part + 3631104;               // 3072
    float* partc   = hc + 3072;                    // 6144
    float* ksg     = partc + 6144;                 // 12288
    float* qsg     = ksg + 12288;                  // 9600
    __hip_bfloat16* lnb  = (__hip_bfloat16*)(qsg + 9600);   // 605184
    __hip_bfloat16* ao   = lnb + 605184;                    // 605184
    __hip_bfloat16* hid  = ao + 605184;                     // 2420736
    __hip_bfloat16* aim  = hid + 2420736;                   // 602112
    __hip_bfloat16* wt   = aim + 602112;                    // 14745600
    ushort* kg  = (ushort*)(wt + 14745600);                 // 786432
    ushort* vgt = kg + 786432;                              // 786432
    ushort* qg  = vgt + 786432;                             // 605184
    __hip_bfloat16* lnb4 = (__hip_bfloat16*)(qg + 605184);  // 3072
    __hip_bfloat16* hid4 = lnb4 + 3072;                     // 12288

    // ---- prologue ----
    prep_all_kernel<<<5388, 256, 0, stream>>>(x, aim, attn_w, proj_w, fc1_w, fc2_w, conv_w, wt, vgt);
    {
        dim3 grid(E_ / 64, 13, 2);
        gemm_mfma_kernel<<<grid, 256, 0, stream>>>(aim, wt + WT_CONV, nullptr, nullptr, nullptr,
                                                   nullptr, part, 784, E_, E_, 0, 2, 0, E_, 0);
    }
    embed_ln_kernel<<<ROWS_, 256, 0, stream>>>(part, part + 602112, conv_b,
                                               pos_e, cls_t, ln1_w, ln1_b, h, lnb);

    // ---- layer 0 (full 788 rows) ----
    {
        const __hip_bfloat16* wl = wt + WT_LBASE;
        {
            dim3 grid(36, 13);     // Q,K,V cols 0..2304, KS=1, fused attn-prep epilogue
            gemm_qkv_kernel<<<grid, 256, 0, stream>>>(lnb, wl + WT_QKV, attn_b,
                                                      qg, qsg, kg, ksg, vgt, 0, 36, nullptr);
        }
        tversky_attn_kernel<<<dim3(13, NH_, B_), 256, 0, stream>>>(
            qg, kg, ksg, vgt, qsg, ao, S_);
        {
            dim3 grid(E_ / 64, 13, 2);
            gemm_mfma_kernel<<<grid, 256, 0, stream>>>(ao, wl + WT_PROJ, nullptr, nullptr, nullptr,
                                                       nullptr, part, ROWS_, E_, E_, 0, 2, 0, E_, 0);
        }
        reduce_ln_kernel<<<ROWS_, 256, 0, stream>>>(part, 2, 605184, proj_b,
                                                    h, ln2_w, ln2_b, lnb);
        {
            dim3 grid(DFF_ / 64, 13);
            gemm_mfma_kernel<<<grid, 256, 0, stream>>>(lnb, wl + WT_FC1, fc1_b,
                                                       nullptr, nullptr, hid, nullptr,
                                                       ROWS_, DFF_, E_, 1, 1, 0, DFF_, 0);
        }
        {
            dim3 grid(E_ / 64, 13, 2);
            gemm_mfma_kernel<<<grid, 256, 0, stream>>>(hid, wl + WT_FC2, nullptr, nullptr, nullptr,
                                                       nullptr, part, ROWS_, E_, DFF_, 0, 2, 0, E_, 0);
        }
        reduce_ln_kernel<<<ROWS_, 256, 0, stream>>>(part, 2, 605184, fc2_b,
                                                    h, ln1_w + E_, ln1_b + E_, lnb);
    }

    // ---- layer 1: only CLS rows (4) needed downstream; K,V GEMM + CLS-Q matvec in ONE launch ----
    {
        const __hip_bfloat16* wl = wt + WT_LBASE + WT_LSTRIDE;
        {
            // x<24: K,V cols 768..2304 (KS=1, fused epilogue); x=24..27: CLS-Q matvec (bb=x-24, hh=y<12)
            dim3 grid(28, 13);
            gemm_qkv_kernel<<<grid, 256, 0, stream>>>(lnb, wl + WT_QKV, attn_b + 3 * E_,
                                                      qg, qsg, kg, ksg, vgt, 768, 24,
                                                      attn_w + (size_t)E_ * 3 * E_);
        }
        tversky_attn_kernel<<<dim3(1, NH_, B_), 256, 0, stream>>>(
            qg, kg, ksg, vgt, qsg, ao, 1);
        {
            dim3 grid(E_ / 64, 1, 1);
            gemm_mfma_kernel<<<grid, 256, 0, stream>>>(ao, wl + WT_PROJ, proj_b + E_, h,
                                                       hc, nullptr, nullptr,
                                                       4, E_, E_, 0, 1, S_ * E_, E_, 0);
        }
        layernorm_kernel<<<4, 256, 0, stream>>>(hc, ln2_w + E_, ln2_b + E_, lnb4);
        {
            dim3 grid(DFF_ / 64, 1, 1);
            gemm_mfma_kernel<<<grid, 256, 0, stream>>>(lnb4, wl + WT_FC1, fc1_b + DFF_,
                                                       nullptr, nullptr, hid4, nullptr,
                                                       4, DFF_, E_, 1, 1, 0, DFF_, 0);
        }
        {
            dim3 grid(E_ / 64, 1, 2);
            gemm_mfma_kernel<<<grid, 256, 0, stream>>>(hid4, wl + WT_FC2, nullptr, nullptr, nullptr,
                                                       nullptr, partc, 4, E_, DFF_, 0, 2, 0, E_, 0);
        }
    }

    {
        dim3 grid((OUT_ + 63) / 64, B_);
        head_ln_kernel<<<grid, 256, 0, stream>>>(hc, partc, partc + 3072, fc2_b + E_,
                                                 lnf_w, lnf_b, head_w, head_b, out);
    }
}